// Round 14
// baseline (240.940 us; speedup 1.0000x reference)
//
#include <hip/hip_runtime.h>
#include <hip/hip_bf16.h>

#define BS 8
#define D 512
#define CCH 128
#define LMAP 8
#define NLAYERS 9

typedef short short8 __attribute__((ext_vector_type(8)));
typedef short short4v __attribute__((ext_vector_type(4)));
typedef float f32x4 __attribute__((ext_vector_type(4)));

// ---- module-global scratch ----
__device__ short g_bufA[(size_t)BS * 4096 * CCH];   // bf16 NHWC [b][px][ci]
__device__ short g_bufB[(size_t)BS * 4096 * CCH];
__device__ float g_w[2][BS * D];
__device__ float g_style_all[NLAYERS * BS * CCH];
__device__ float g_rstd_all[NLAYERS * BS * CCH];
__device__ float g_s2[(size_t)NLAYERS * CCH * CCH];              // S2[l][co][ci] = sum_tap w^2
__device__ short g_wpack[(size_t)NLAYERS * 9 * 4 * 8 * 64 * 8];  // packed bf16 W-frags
__device__ short g_rgbpack[9 * 4 * 64 * 8];
__device__ float g_mapwT[(size_t)LMAP * D * D];                  // map_w transposed [l][j][k]
__device__ float g_AwT[(size_t)LMAP * CCH * D];                  // A_w transposed [l][c][k] (layers 1..8 at idx l-1? no: [l]=0..7 -> layer l+1 uses idx l)

__device__ __forceinline__ float leaky(float v) { return v >= 0.f ? v : 0.2f * v; }
__device__ __forceinline__ short f2b(float f) {
    __hip_bfloat16 h = __float2bfloat16(f);
    return *reinterpret_cast<short*>(&h);
}
__device__ __forceinline__ float b2f(short s) {
    return __uint_as_float(((unsigned int)(unsigned short)s) << 16);
}
__device__ __forceinline__ int swz(int col) { return ((col ^ (col >> 3)) & 7) << 3; }

__device__ __forceinline__ void uptaps(int o, int Win, int& i0, int& i1, float& w0, float& w1)
{
    int m = o >> 1;
    if ((o & 1) == 0) { i0 = m - 1; i1 = m; w0 = 0.25f; w1 = 0.75f; if (i0 < 0) { i0 = 0; w0 = 0.f; w1 = 1.f; } }
    else              { i0 = m; i1 = m + 1; w0 = 0.75f; w1 = 0.25f; if (i1 >= Win) { i1 = Win - 1; w0 = 1.f; w1 = 0.f; } }
}

// ---------------- fused prep: wpack + rgbpack + S2 + mapW^T + AwT ----------------
#define WPN (NLAYERS * 9 * 4 * 8 * 64)
#define RGBN (9 * 4 * 64)
#define S2N (NLAYERS * CCH * CCH)
#define MTN (LMAP * D * (D / 4))          // 524288: [l][k][j4] float4 reads
#define ATN (LMAP * D * (CCH / 4))        // 131072: [l][k][c4]
#define PTOT (WPN + RGBN + S2N + MTN + ATN)
__global__ __launch_bounds__(256) void prep_kernel(
    const float* __restrict__ convw, const float* __restrict__ rgbw,
    const float* __restrict__ mapw, const float* __restrict__ Aw)
{
    int idx = blockIdx.x * 256 + threadIdx.x;
    if (idx < WPN) {
        int lane = idx & 63;
        int cogrp = (idx >> 6) & 7;
        int chunk = (idx >> 9) & 3;
        int t = idx >> 11;
        int layer = t / 9, tap = t - layer * 9;
        int co = cogrp * 16 + (lane & 15);
        int ci0 = chunk * 32 + (lane >> 4) * 8;
        short8 v;
#pragma unroll
        for (int j = 0; j < 8; ++j)
            v[j] = f2b(convw[(((size_t)layer * CCH + co) * CCH + ci0 + j) * 9 + tap]);
        *reinterpret_cast<short8*>(&g_wpack[(size_t)idx * 8]) = v;
    } else if (idx < WPN + RGBN) {
        int u = idx - WPN;
        int lane = u & 63;
        int chunk = (u >> 6) & 3;
        int tap = u >> 8;
        int co = lane & 15;
        int ci0 = chunk * 32 + (lane >> 4) * 8;
        short8 v;
#pragma unroll
        for (int j = 0; j < 8; ++j)
            v[j] = (co < 3) ? f2b(rgbw[((size_t)(co * CCH) + ci0 + j) * 9 + tap]) : (short)0;
        *reinterpret_cast<short8*>(&g_rgbpack[(size_t)u * 8]) = v;
    } else if (idx < WPN + RGBN + S2N) {
        int u = idx - WPN - RGBN;         // [l][co][ci]
        const float* wp = convw + (size_t)u * 9;
        float s = 0.f;
#pragma unroll
        for (int t = 0; t < 9; ++t) { float m = wp[t]; s += m * m; }
        g_s2[u] = s;
    } else if (idx < WPN + RGBN + S2N + MTN) {
        int u = idx - WPN - RGBN - S2N;   // [l][k][j4]
        int j4 = u & 127;
        int k = (u >> 7) & 511;
        int l = u >> 16;
        float4 v = *reinterpret_cast<const float4*>(&mapw[(((size_t)l * D + k) * D) + j4 * 4]);
        g_mapwT[(((size_t)l * D + j4 * 4 + 0) * D) + k] = v.x;
        g_mapwT[(((size_t)l * D + j4 * 4 + 1) * D) + k] = v.y;
        g_mapwT[(((size_t)l * D + j4 * 4 + 2) * D) + k] = v.z;
        g_mapwT[(((size_t)l * D + j4 * 4 + 3) * D) + k] = v.w;
    } else if (idx < PTOT) {
        int u = idx - WPN - RGBN - S2N - MTN;  // [l][k][c4]
        int c4 = u & 31;
        int k = (u >> 5) & 511;
        int l = u >> 14;
        float4 v = *reinterpret_cast<const float4*>(&Aw[(((size_t)l * D + k) * CCH) + c4 * 4]);
        g_AwT[(((size_t)l * CCH + c4 * 4 + 0) * D) + k] = v.x;
        g_AwT[(((size_t)l * CCH + c4 * 4 + 1) * D) + k] = v.y;
        g_AwT[(((size_t)l * CCH + c4 * 4 + 2) * D) + k] = v.z;
        g_AwT[(((size_t)l * CCH + c4 * 4 + 3) * D) + k] = v.w;
    }
}

// ---------------- Mapping FC (transposed weights: contiguous float4 k-loads) ----------------
__global__ __launch_bounds__(256) void map_fc_kernel(
    int srcSel, int useZ, int layer, const float* __restrict__ z,
    const float* __restrict__ bias)
{
    float* wout = g_w[srcSel ^ 1];
    int b = blockIdx.y;
    int jb = blockIdx.x * 64;
    int tid = threadIdx.x;
    int jl = tid & 63, kp = tid >> 6;
    __shared__ __align__(16) float xin[D];
    __shared__ float part[4][64];
    __shared__ float wred[4];
    if (useZ) {
        xin[tid] = z[b * D + tid];
        xin[tid + 256] = z[b * D + tid + 256];
    } else {
        const float* win = g_w[srcSel];
        xin[tid] = win[b * D + tid];
        xin[tid + 256] = win[b * D + tid + 256];
    }
    __syncthreads();
    if (useZ) {
        float p = xin[tid] * xin[tid] + xin[tid + 256] * xin[tid + 256];
#pragma unroll
        for (int off = 32; off > 0; off >>= 1) p += __shfl_down(p, off, 64);
        if ((tid & 63) == 0) wred[tid >> 6] = p;
        __syncthreads();
        float ss = wred[0] + wred[1] + wred[2] + wred[3];
        float r = rsqrtf(ss * (1.f / 512.f) + 1e-8f);
        xin[tid] *= r; xin[tid + 256] *= r;
        __syncthreads();
    }
    const float4* Wt4 = reinterpret_cast<const float4*>(
        g_mapwT + (((size_t)layer * D + jb + jl) * D) + kp * 128);
    const float4* x4 = reinterpret_cast<const float4*>(&xin[kp * 128]);
    float a0 = 0.f, a1 = 0.f, a2 = 0.f, a3 = 0.f;
#pragma unroll
    for (int i = 0; i < 32; i += 4) {
        float4 w0 = Wt4[i + 0], w1 = Wt4[i + 1], w2 = Wt4[i + 2], w3 = Wt4[i + 3];
        float4 v0 = x4[i + 0], v1 = x4[i + 1], v2 = x4[i + 2], v3 = x4[i + 3];
        a0 = fmaf(w0.x, v0.x, fmaf(w0.y, v0.y, fmaf(w0.z, v0.z, fmaf(w0.w, v0.w, a0))));
        a1 = fmaf(w1.x, v1.x, fmaf(w1.y, v1.y, fmaf(w1.z, v1.z, fmaf(w1.w, v1.w, a1))));
        a2 = fmaf(w2.x, v2.x, fmaf(w2.y, v2.y, fmaf(w2.z, v2.z, fmaf(w2.w, v2.w, a2))));
        a3 = fmaf(w3.x, v3.x, fmaf(w3.y, v3.y, fmaf(w3.z, v3.z, fmaf(w3.w, v3.w, a3))));
    }
    part[kp][jl] = (a0 + a1) + (a2 + a3);
    __syncthreads();
    if (tid < 64) {
        float s = part[0][tid] + part[1][tid] + part[2][tid] + part[3][tid] + bias[jb + tid];
        wout[b * D + jb + tid] = leaky(s);
    }
}

// ---------------- style + rstd for ALL layers (AwT contiguous loads; rstd via S2) ----------------
__global__ __launch_bounds__(256) void style_rstd_kernel(const float* __restrict__ Ab)
{
    int l = blockIdx.x + 1;        // layers 1..8 (AwT index l-1... note Aw layout is [NLAYERS][D][CCH], we packed l=0..7 as-is)
    int b = blockIdx.y;
    int tid = threadIdx.x;
    __shared__ __align__(16) float ws_[D];
    __shared__ float part[2][CCH];
    __shared__ float st[CCH];
    ws_[tid] = g_w[0][b * D + tid];
    ws_[tid + 256] = g_w[0][b * D + tid + 256];
    __syncthreads();
    {
        int c = tid & 127, kh = tid >> 7;
        // g_AwT packed from Aw[l][k][c] for l = 0..7; reference layer index = l (A_w has NLAYERS=9 rows,
        // but we only packed the first 8? No: we packed LMAP=8 l-slices of Aw, i.e. layers 0..7.
        // Synthesis uses layers 1..8 -> pack must cover index 1..8. Handled at launch by passing A_w + D*CCH.
        const float4* Ap4 = reinterpret_cast<const float4*>(
            g_AwT + (((size_t)(l - 1) * CCH + c) * D) + kh * 256);
        const float4* v4 = reinterpret_cast<const float4*>(&ws_[kh * 256]);
        float a0 = 0.f, a1 = 0.f, a2 = 0.f, a3 = 0.f;
#pragma unroll
        for (int i = 0; i < 64; i += 4) {
            float4 w0 = Ap4[i + 0], w1 = Ap4[i + 1], w2 = Ap4[i + 2], w3 = Ap4[i + 3];
            float4 x0 = v4[i + 0], x1 = v4[i + 1], x2 = v4[i + 2], x3 = v4[i + 3];
            a0 = fmaf(w0.x, x0.x, fmaf(w0.y, x0.y, fmaf(w0.z, x0.z, fmaf(w0.w, x0.w, a0))));
            a1 = fmaf(w1.x, x1.x, fmaf(w1.y, x1.y, fmaf(w1.z, x1.z, fmaf(w1.w, x1.w, a1))));
            a2 = fmaf(w2.x, x2.x, fmaf(w2.y, x2.y, fmaf(w2.z, x2.z, fmaf(w2.w, x2.w, a2))));
            a3 = fmaf(w3.x, x3.x, fmaf(w3.y, x3.y, fmaf(w3.z, x3.z, fmaf(w3.w, x3.w, a3))));
        }
        part[kh][c] = (a0 + a1) + (a2 + a3);
    }
    __syncthreads();
    if (tid < CCH) {
        float s = part[0][tid] + part[1][tid] + Ab[l * CCH + tid];
        st[tid] = s;
        g_style_all[((size_t)l * BS + b) * CCH + tid] = s;
    }
    __syncthreads();
    int colid = tid >> 4, kpart = tid & 15;
#pragma unroll
    for (int co8 = 0; co8 < 8; ++co8) {
        int cout = co8 * 16 + colid;
        const float* sp = g_s2 + ((size_t)l * CCH + cout) * CCH + kpart * 8;
        float s = 0.f;
#pragma unroll
        for (int j = 0; j < 8; ++j) { float sv = st[kpart * 8 + j]; s += sv * sv * sp[j]; }
#pragma unroll
        for (int off = 8; off > 0; off >>= 1) s += __shfl_down(s, off, 16);
        if (kpart == 0) g_rstd_all[((size_t)l * BS + b) * CCH + cout] = rsqrtf(s + 1e-8f);
    }
}

// ---------------- fused conv layers 1+2 (both 8x8), one block per batch ----------------
__global__ __launch_bounds__(256) void conv8_pair_kernel(
    const float* __restrict__ noise,
    const float* __restrict__ Bw, const float* __restrict__ Bb)
{
    constexpr int W = 8, SW = 10, ROWS = 10, NS = 64, WIN = 4;
    const int b = blockIdx.x;
    const int tid = threadIdx.x;
    const int lane = tid & 63;
    const int wave = tid >> 6;
    const int wpx = wave & 1;
    const int wco = wave >> 1;

    __shared__ short xs1[ROWS * SW * CCH];
    __shared__ short xs2[ROWS * SW * CCH];
    __shared__ short sm[16 * CCH];
    __shared__ float style2_s[CCH], style3_s[CCH];

    if (tid < CCH) {
        style2_s[tid] = g_style_all[((size_t)2 * BS + b) * CCH + tid];
        style3_s[tid] = g_style_all[((size_t)3 * BS + b) * CCH + tid];
    }
    for (int u = tid; u < 16 * CCH; u += 256) {
        int c = u & 127;
        int pp = u >> 7;
        float v = leaky(noise[b * 4096 + pp] * Bw[c] + Bb[c])
                  * g_style_all[((size_t)1 * BS + b) * CCH + c];
        sm[u] = f2b(v);
    }
    for (int u = tid; u < ROWS * SW * 16; u += 256) {
        int ck = u & 15;
        int cell = u >> 4;
        int col = cell % SW;
        int rr = cell / SW;
        if (rr >= 1 && rr <= 8 && col >= 1 && col <= 8) continue;
        short8 zz = {0, 0, 0, 0, 0, 0, 0, 0};
        *reinterpret_cast<short8*>(&xs2[(((rr * SW + col) * CCH) + ck * 8) ^ swz(col)]) = zz;
    }
    __syncthreads();

    for (int u = tid; u < ROWS * SW * 16; u += 256) {
        int ck = u & 15;
        int rem = u >> 4;
        int col = rem % SW;
        int rr = rem / SW;
        int gy = rr - 1, gx = col - 1;
        short8 v = {0, 0, 0, 0, 0, 0, 0, 0};
        if (gy >= 0 && gy < W && gx >= 0 && gx < W) {
            int y0, y1, x0, x1; float wy0, wy1, wx0, wx1;
            uptaps(gy, WIN, y0, y1, wy0, wy1);
            uptaps(gx, WIN, x0, x1, wx0, wx1);
            short8 a00 = *reinterpret_cast<const short8*>(&sm[((size_t)y0 * WIN + x0) * CCH + ck * 8]);
            short8 a01 = *reinterpret_cast<const short8*>(&sm[((size_t)y0 * WIN + x1) * CCH + ck * 8]);
            short8 a10 = *reinterpret_cast<const short8*>(&sm[((size_t)y1 * WIN + x0) * CCH + ck * 8]);
            short8 a11 = *reinterpret_cast<const short8*>(&sm[((size_t)y1 * WIN + x1) * CCH + ck * 8]);
            float w00 = wy0 * wx0, w01 = wy0 * wx1, w10 = wy1 * wx0, w11 = wy1 * wx1;
#pragma unroll
            for (int j = 0; j < 8; ++j)
                v[j] = f2b(w00 * b2f(a00[j]) + w01 * b2f(a01[j])
                         + w10 * b2f(a10[j]) + w11 * b2f(a11[j]));
        }
        *reinterpret_cast<short8*>(&xs1[(((rr * SW + col) * CCH) + ck * 8) ^ swz(col)]) = v;
    }
    __syncthreads();

    int rL[2], cL[2];
#pragma unroll
    for (int pf = 0; pf < 2; ++pf) {
        int pl = (wpx * 2 + pf) * 16 + (lane & 15);
        cL[pf] = pl & (W - 1);
        rL[pf] = pl >> 3;
    }
    const int grpoff = (lane >> 4) * 8;

    // phase A: conv layer 1 -> xs2
    {
        f32x4 acc[2][4] = {};
        const short* wl = g_wpack + ((size_t)1 * 9 * 4 * 8 * 64 + (size_t)(wco * 4) * 64 + lane) * 8;
        short8 wc0 = *reinterpret_cast<const short8*>(wl);
        short8 wc1 = *reinterpret_cast<const short8*>(wl + 512);
        short8 wc2 = *reinterpret_cast<const short8*>(wl + 1024);
        short8 wc3 = *reinterpret_cast<const short8*>(wl + 1536);
#pragma unroll
        for (int k = 0; k < 36; ++k) {
            short8 wn0 = wc0, wn1 = wc1, wn2 = wc2, wn3 = wc3;
            if (k + 1 < 36) {
                const short* wk = wl + (size_t)(k + 1) * 4096;
                wn0 = *reinterpret_cast<const short8*>(wk);
                wn1 = *reinterpret_cast<const short8*>(wk + 512);
                wn2 = *reinterpret_cast<const short8*>(wk + 1024);
                wn3 = *reinterpret_cast<const short8*>(wk + 1536);
            }
            const int tap = k >> 2, ch = k & 3;
            const int ky = tap / 3, kx = tap - ky * 3;
#pragma unroll
            for (int pf = 0; pf < 2; ++pf) {
                int col = cL[pf] + kx;
                int idx = (((rL[pf] + ky) * SW + col) * CCH + (ch << 5) + grpoff) ^ swz(col);
                short8 xf = *reinterpret_cast<const short8*>(&xs1[idx]);
                acc[pf][0] = __builtin_amdgcn_mfma_f32_16x16x32_bf16(wc0, xf, acc[pf][0], 0, 0, 0);
                acc[pf][1] = __builtin_amdgcn_mfma_f32_16x16x32_bf16(wc1, xf, acc[pf][1], 0, 0, 0);
                acc[pf][2] = __builtin_amdgcn_mfma_f32_16x16x32_bf16(wc2, xf, acc[pf][2], 0, 0, 0);
                acc[pf][3] = __builtin_amdgcn_mfma_f32_16x16x32_bf16(wc3, xf, acc[pf][3], 0, 0, 0);
            }
            wc0 = wn0; wc1 = wn1; wc2 = wn2; wc3 = wn3;
        }
        float nz[2];
#pragma unroll
        for (int pf = 0; pf < 2; ++pf)
            nz[pf] = noise[(size_t)BS * 4096 + b * 4096 + (wpx * 2 + pf) * 16 + (lane & 15)];
#pragma unroll
        for (int cf = 0; cf < 4; ++cf) {
            const int coB = (wco * 4 + cf) * 16 + (lane >> 4) * 4;
            float rs[4], bw[4], bb[4], sn[4];
#pragma unroll
            for (int r = 0; r < 4; ++r) {
                rs[r] = g_rstd_all[((size_t)1 * BS + b) * CCH + coB + r];
                bw[r] = Bw[1 * CCH + coB + r];
                bb[r] = Bb[1 * CCH + coB + r];
                sn[r] = style2_s[coB + r];
            }
#pragma unroll
            for (int pf = 0; pf < 2; ++pf) {
                int px = (wpx * 2 + pf) * 16 + (lane & 15);
                int y = px >> 3, x = px & 7;
                short4v o;
#pragma unroll
                for (int r = 0; r < 4; ++r)
                    o[r] = f2b(leaky(acc[pf][cf][r] * rs[r] + nz[pf] * bw[r] + bb[r]) * sn[r]);
                int col = x + 1;
                *reinterpret_cast<short4v*>(&xs2[((((y + 1) * SW + col) * CCH) + coB) ^ swz(col)]) = o;
            }
        }
    }
    __syncthreads();

    // phase B: conv layer 2 -> global
    {
        f32x4 acc[2][4] = {};
        const short* wl = g_wpack + ((size_t)2 * 9 * 4 * 8 * 64 + (size_t)(wco * 4) * 64 + lane) * 8;
        short8 wc0 = *reinterpret_cast<const short8*>(wl);
        short8 wc1 = *reinterpret_cast<const short8*>(wl + 512);
        short8 wc2 = *reinterpret_cast<const short8*>(wl + 1024);
        short8 wc3 = *reinterpret_cast<const short8*>(wl + 1536);
#pragma unroll
        for (int k = 0; k < 36; ++k) {
            short8 wn0 = wc0, wn1 = wc1, wn2 = wc2, wn3 = wc3;
            if (k + 1 < 36) {
                const short* wk = wl + (size_t)(k + 1) * 4096;
                wn0 = *reinterpret_cast<const short8*>(wk);
                wn1 = *reinterpret_cast<const short8*>(wk + 512);
                wn2 = *reinterpret_cast<const short8*>(wk + 1024);
                wn3 = *reinterpret_cast<const short8*>(wk + 1536);
            }
            const int tap = k >> 2, ch = k & 3;
            const int ky = tap / 3, kx = tap - ky * 3;
#pragma unroll
            for (int pf = 0; pf < 2; ++pf) {
                int col = cL[pf] + kx;
                int idx = (((rL[pf] + ky) * SW + col) * CCH + (ch << 5) + grpoff) ^ swz(col);
                short8 xf = *reinterpret_cast<const short8*>(&xs2[idx]);
                acc[pf][0] = __builtin_amdgcn_mfma_f32_16x16x32_bf16(wc0, xf, acc[pf][0], 0, 0, 0);
                acc[pf][1] = __builtin_amdgcn_mfma_f32_16x16x32_bf16(wc1, xf, acc[pf][1], 0, 0, 0);
                acc[pf][2] = __builtin_amdgcn_mfma_f32_16x16x32_bf16(wc2, xf, acc[pf][2], 0, 0, 0);
                acc[pf][3] = __builtin_amdgcn_mfma_f32_16x16x32_bf16(wc3, xf, acc[pf][3], 0, 0, 0);
            }
            wc0 = wn0; wc1 = wn1; wc2 = wn2; wc3 = wn3;
        }
        float nz[2];
#pragma unroll
        for (int pf = 0; pf < 2; ++pf)
            nz[pf] = noise[(size_t)2 * BS * 4096 + b * 4096 + (wpx * 2 + pf) * 16 + (lane & 15)];
#pragma unroll
        for (int cf = 0; cf < 4; ++cf) {
            const int coB = (wco * 4 + cf) * 16 + (lane >> 4) * 4;
            float rs[4], bw[4], bb[4], sn[4];
#pragma unroll
            for (int r = 0; r < 4; ++r) {
                rs[r] = g_rstd_all[((size_t)2 * BS + b) * CCH + coB + r];
                bw[r] = Bw[2 * CCH + coB + r];
                bb[r] = Bb[2 * CCH + coB + r];
                sn[r] = style3_s[coB + r];
            }
#pragma unroll
            for (int pf = 0; pf < 2; ++pf) {
                int px = (wpx * 2 + pf) * 16 + (lane & 15);
                short4v o;
#pragma unroll
                for (int r = 0; r < 4; ++r)
                    o[r] = f2b(leaky(acc[pf][cf][r] * rs[r] + nz[pf] * bw[r] + bb[r]) * sn[r]);
                *reinterpret_cast<short4v*>(&g_bufA[((size_t)b * NS + px) * CCH + coB]) = o;
            }
        }
    }
}

// ---------------- MFMA modulated conv (NHWC bf16), layers 3..8 ----------------
template<int LW, int UPM, int TLW>
__global__ __launch_bounds__(256) void conv_mfma_kernel(
    int srcSel, int layer, int layerNext,
    const float* __restrict__ noise,
    const float* __restrict__ Bw, const float* __restrict__ Bb)
{
    constexpr int W = 1 << LW;
    constexpr int TW = 1 << TLW;
    constexpr int TH = 64 >> TLW;
    constexpr int SW = TW + 2;
    constexpr int ROWS = TH + 2;
    constexpr int NS = W * W;
    constexpr int WIN = W / 2;
    constexpr int TILES_X = W / TW;

    const short* xin = srcSel ? g_bufB : g_bufA;
    short* xout = srcSel ? g_bufA : g_bufB;

    const int b = blockIdx.y;
    const int tx = blockIdx.x & (TILES_X - 1);
    const int ty = blockIdx.x >> (LW - TLW);
    const int rowBase = ty * TH;
    const int colBase = tx * TW;
    const int tid = threadIdx.x;
    const int lane = tid & 63;
    const int wave = tid >> 6;
    const int wpx = wave & 1;
    const int wco = wave >> 1;

    __shared__ short xs[ROWS * SW * CCH];
    __shared__ float style_s[CCH];

    if (tid < CCH)
        style_s[tid] = layerNext ? g_style_all[((size_t)layerNext * BS + b) * CCH + tid] : 1.f;

    {
        const short* src = xin + (size_t)b * NS * CCH;
        const short* srcH = xin + (size_t)b * WIN * WIN * CCH;
        constexpr int UN = ROWS * SW * 16;
        for (int u = tid; u < UN; u += 256) {
            int ck = u & 15;
            int rem = u >> 4;
            int col = rem % SW;
            int rr = rem / SW;
            int gy = rowBase + rr - 1, gx = colBase + col - 1;
            short8 v = {0, 0, 0, 0, 0, 0, 0, 0};
            if (gy >= 0 && gy < W && gx >= 0 && gx < W) {
                if (UPM == 0) {
                    v = *reinterpret_cast<const short8*>(&src[((size_t)gy * W + gx) * CCH + ck * 8]);
                } else {
                    int y0, y1, x0, x1; float wy0, wy1, wx0, wx1;
                    uptaps(gy, WIN, y0, y1, wy0, wy1);
                    uptaps(gx, WIN, x0, x1, wx0, wx1);
                    short8 a00 = *reinterpret_cast<const short8*>(&srcH[((size_t)y0 * WIN + x0) * CCH + ck * 8]);
                    short8 a01 = *reinterpret_cast<const short8*>(&srcH[((size_t)y0 * WIN + x1) * CCH + ck * 8]);
                    short8 a10 = *reinterpret_cast<const short8*>(&srcH[((size_t)y1 * WIN + x0) * CCH + ck * 8]);
                    short8 a11 = *reinterpret_cast<const short8*>(&srcH[((size_t)y1 * WIN + x1) * CCH + ck * 8]);
                    float w00 = wy0 * wx0, w01 = wy0 * wx1, w10 = wy1 * wx0, w11 = wy1 * wx1;
#pragma unroll
                    for (int j = 0; j < 8; ++j)
                        v[j] = f2b(w00 * b2f(a00[j]) + w01 * b2f(a01[j])
                                 + w10 * b2f(a10[j]) + w11 * b2f(a11[j]));
                }
            }
            *reinterpret_cast<short8*>(&xs[(((rr * SW + col) * CCH) + ck * 8) ^ swz(col)]) = v;
        }
    }
    __syncthreads();

    int rL[2], cL[2];
#pragma unroll
    for (int pf = 0; pf < 2; ++pf) {
        int pl = (wpx * 2 + pf) * 16 + (lane & 15);
        cL[pf] = pl & (TW - 1);
        rL[pf] = pl >> TLW;
    }
    const int grpoff = (lane >> 4) * 8;

    f32x4 acc[2][4] = {};
    const short* wl = g_wpack + ((size_t)layer * 9 * 4 * 8 * 64
                                 + (size_t)(wco * 4) * 64 + lane) * 8;

    short8 wc0 = *reinterpret_cast<const short8*>(wl);
    short8 wc1 = *reinterpret_cast<const short8*>(wl + 512);
    short8 wc2 = *reinterpret_cast<const short8*>(wl + 1024);
    short8 wc3 = *reinterpret_cast<const short8*>(wl + 1536);
#pragma unroll
    for (int k = 0; k < 36; ++k) {
        short8 wn0 = wc0, wn1 = wc1, wn2 = wc2, wn3 = wc3;
        if (k + 1 < 36) {
            const short* wk = wl + (size_t)(k + 1) * 4096;
            wn0 = *reinterpret_cast<const short8*>(wk);
            wn1 = *reinterpret_cast<const short8*>(wk + 512);
            wn2 = *reinterpret_cast<const short8*>(wk + 1024);
            wn3 = *reinterpret_cast<const short8*>(wk + 1536);
        }
        const int tap = k >> 2, ch = k & 3;
        const int ky = tap / 3, kx = tap - ky * 3;
#pragma unroll
        for (int pf = 0; pf < 2; ++pf) {
            int col = cL[pf] + kx;
            int idx = (((rL[pf] + ky) * SW + col) * CCH + (ch << 5) + grpoff) ^ swz(col);
            short8 xf = *reinterpret_cast<const short8*>(&xs[idx]);
            acc[pf][0] = __builtin_amdgcn_mfma_f32_16x16x32_bf16(wc0, xf, acc[pf][0], 0, 0, 0);
            acc[pf][1] = __builtin_amdgcn_mfma_f32_16x16x32_bf16(wc1, xf, acc[pf][1], 0, 0, 0);
            acc[pf][2] = __builtin_amdgcn_mfma_f32_16x16x32_bf16(wc2, xf, acc[pf][2], 0, 0, 0);
            acc[pf][3] = __builtin_amdgcn_mfma_f32_16x16x32_bf16(wc3, xf, acc[pf][3], 0, 0, 0);
        }
        wc0 = wn0; wc1 = wn1; wc2 = wn2; wc3 = wn3;
    }

    float nz[2];
    int pxg[2];
#pragma unroll
    for (int pf = 0; pf < 2; ++pf) {
        int pl = (wpx * 2 + pf) * 16 + (lane & 15);
        int x = pl & (TW - 1), y = pl >> TLW;
        pxg[pf] = (rowBase + y) * W + colBase + x;
        nz[pf] = noise[b * 4096 + pxg[pf]];
    }
#pragma unroll
    for (int cf = 0; cf < 4; ++cf) {
        const int coB = (wco * 4 + cf) * 16 + (lane >> 4) * 4;
        float rs[4], bw[4], bb[4], sn[4];
#pragma unroll
        for (int r = 0; r < 4; ++r) {
            rs[r] = g_rstd_all[((size_t)layer * BS + b) * CCH + coB + r];
            bw[r] = Bw[coB + r];
            bb[r] = Bb[coB + r];
            sn[r] = style_s[coB + r];
        }
#pragma unroll
        for (int pf = 0; pf < 2; ++pf) {
            short4v o;
#pragma unroll
            for (int r = 0; r < 4; ++r) {
                float v = leaky(acc[pf][cf][r] * rs[r] + nz[pf] * bw[r] + bb[r]) * sn[r];
                o[r] = f2b(v);
            }
            *reinterpret_cast<short4v*>(&xout[((size_t)b * NS + pxg[pf]) * CCH + coB]) = o;
        }
    }
}

// ---------------- MFMA toRGB (W=64; 32x2 tiles; 3 real rows in 16-row M; waves split K) ----------------
__global__ __launch_bounds__(256) void rgb_mfma_kernel(
    int srcSel, const float* __restrict__ rgbb, float* __restrict__ out)
{
    constexpr int W = 64, TW = 32, TH = 2, SW = 34, ROWS = 4, NS = 4096;
    const short* xin = srcSel ? g_bufB : g_bufA;

    const int b = blockIdx.y;
    const int tx = blockIdx.x & 1;
    const int ty = blockIdx.x >> 1;
    const int rowBase = ty * TH;
    const int colBase = tx * TW;
    const int tid = threadIdx.x;
    const int lane = tid & 63;
    const int wave = tid >> 6;     // K-chunk

    __shared__ short xs[ROWS * SW * CCH];

    {
        const short* src = xin + (size_t)b * NS * CCH;
        constexpr int UN = ROWS * SW * 16;
        for (int u = tid; u < UN; u += 256) {
            int ck = u & 15;
            int rem = u >> 4;
            int col = rem % SW;
            int rr = rem / SW;
            int gy = rowBase + rr - 1, gx = colBase + col - 1;
            short8 v = {0, 0, 0, 0, 0, 0, 0, 0};
            if (gy >= 0 && gy < W && gx >= 0 && gx < W)
                v = *reinterpret_cast<const short8*>(&src[((size_t)gy * W + gx) * CCH + ck * 8]);
            *reinterpret_cast<short8*>(&xs[(((rr * SW + col) * CCH) + ck * 8) ^ swz(col)]) = v;
        }
    }
    __syncthreads();

    const int grpoff = (lane >> 4) * 8;
    const int cl = lane & 15;
    f32x4 acc[4] = {};
#pragma unroll
    for (int tap = 0; tap < 9; ++tap) {
        const int ky = tap / 3, kx = tap - ky * 3;
        short8 wf = *reinterpret_cast<const short8*>(
            &g_rgbpack[((size_t)(tap * 4 + wave) * 64 + lane) * 8]);
#pragma unroll
        for (int pf = 0; pf < 4; ++pf) {
            int pl = pf * 16 + cl;
            int x = pl & (TW - 1), y = pl >> 5;
            int col = x + kx;
            int idx = (((y + ky) * SW + col) * CCH + (wave << 5) + grpoff) ^ swz(col);
            short8 xf = *reinterpret_cast<const short8*>(&xs[idx]);
            acc[pf] = __builtin_amdgcn_mfma_f32_16x16x32_bf16(wf, xf, acc[pf], 0, 0, 0);
        }
    }
    __syncthreads();
    float* red = reinterpret_cast<float*>(xs);
    if (wave > 0) {
#pragma unroll
        for (int pf = 0; pf < 4; ++pf)
#pragma unroll
            for (int r = 0; r < 4; ++r)
                red[(((wave - 1) * 4 + pf) * 64 + lane) * 4 + r] = acc[pf][r];
    }
    __syncthreads();
    if (wave == 0 && (lane >> 4) == 0) {
#pragma unroll
        for (int pf = 0; pf < 4; ++pf) {
            int pl = pf * 16 + cl;
            int x = pl & (TW - 1), y = pl >> 5;
            int px = (rowBase + y) * W + colBase + x;
#pragma unroll
            for (int r = 0; r < 3; ++r) {
                float s = acc[pf][r];
#pragma unroll
                for (int wv = 0; wv < 3; ++wv)
                    s += red[((wv * 4 + pf) * 64 + lane) * 4 + r];
                out[(size_t)(b * 3 + r) * NS + px] = s + rgbb[r];
            }
        }
    }
}

// ---------------- launch ----------------
extern "C" void kernel_launch(void* const* d_in, const int* in_sizes, int n_in,
                              void* d_out, int out_size, void* d_ws, size_t ws_size,
                              hipStream_t stream)
{
    const float* latent = (const float*)d_in[0];
    const float* noise  = (const float*)d_in[1];
    const float* map_w  = (const float*)d_in[2];
    const float* map_b  = (const float*)d_in[3];
    const float* A_w    = (const float*)d_in[4];
    const float* A_b    = (const float*)d_in[5];
    const float* B_w    = (const float*)d_in[6];
    const float* B_b    = (const float*)d_in[7];
    const float* conv_w = (const float*)d_in[8];
    const float* rgb_w  = (const float*)d_in[9];
    const float* rgb_b  = (const float*)d_in[10];
    float* out = (float*)d_out;
    (void)d_ws; (void)ws_size;

    // pack AwT from layers 1..8 (synthesis layers); pass A_w offset by one layer slice
    prep_kernel<<<(PTOT + 255) / 256, 256, 0, stream>>>(conv_w, rgb_w, map_w, A_w + (size_t)D * CCH);

    int wsel = 0;
    for (int i = 0; i < LMAP; ++i) {
        map_fc_kernel<<<dim3(8, BS), 256, 0, stream>>>(
            wsel, i == 0 ? 1 : 0, i, latent, map_b + i * D);
        wsel ^= 1;
    }

    style_rstd_kernel<<<dim3(8, BS), 256, 0, stream>>>(A_b);

    conv8_pair_kernel<<<BS, 256, 0, stream>>>(noise, B_w, B_b);

    int cur = 0;   // data in g_bufA
    int Hc = 8;
    for (int i = 3; i < NLAYERS; ++i) {
        if (i & 1) Hc *= 2;
        int ns = Hc * Hc;
        int lnext = (i < 8) ? (i + 1) : 0;
        dim3 grid(ns / 64, BS);
        const float* nz = noise + (size_t)i * BS * 4096;
        switch (i) {
            case 3: conv_mfma_kernel<4, 1, 4><<<grid, 256, 0, stream>>>(cur, i, lnext, nz, B_w + i * CCH, B_b + i * CCH); break;
            case 4: conv_mfma_kernel<4, 0, 4><<<grid, 256, 0, stream>>>(cur, i, lnext, nz, B_w + i * CCH, B_b + i * CCH); break;
            case 5: conv_mfma_kernel<5, 1, 5><<<grid, 256, 0, stream>>>(cur, i, lnext, nz, B_w + i * CCH, B_b + i * CCH); break;
            case 6: conv_mfma_kernel<5, 0, 5><<<grid, 256, 0, stream>>>(cur, i, lnext, nz, B_w + i * CCH, B_b + i * CCH); break;
            case 7: conv_mfma_kernel<6, 1, 5><<<grid, 256, 0, stream>>>(cur, i, lnext, nz, B_w + i * CCH, B_b + i * CCH); break;
            case 8: conv_mfma_kernel<6, 0, 5><<<grid, 256, 0, stream>>>(cur, i, lnext, nz, B_w + i * CCH, B_b + i * CCH); break;
        }
        cur ^= 1;
    }

    rgb_mfma_kernel<<<dim3(64, BS), 256, 0, stream>>>(cur, rgb_b, out);
}

// Round 15
// 199.327 us; speedup vs baseline: 1.2088x; 1.2088x over previous
//
#include <hip/hip_runtime.h>
#include <hip/hip_bf16.h>

#define BS 8
#define D 512
#define CCH 128
#define LMAP 8
#define NLAYERS 9

typedef short short8 __attribute__((ext_vector_type(8)));
typedef short short4v __attribute__((ext_vector_type(4)));
typedef float f32x4 __attribute__((ext_vector_type(4)));

// ---- module-global scratch ----
__device__ short g_bufA[(size_t)BS * 4096 * CCH];   // bf16 NHWC [b][px][ci]
__device__ short g_bufB[(size_t)BS * 4096 * CCH];
__device__ float g_w[2][BS * D];
__device__ float g_style_all[NLAYERS * BS * CCH];
__device__ float g_rstd_all[NLAYERS * BS * CCH];
__device__ float g_s2[(size_t)NLAYERS * CCH * CCH];              // S2[l][co][ci] = sum_tap w^2
__device__ short g_wpack[(size_t)NLAYERS * 9 * 4 * 8 * 64 * 8];  // packed bf16 W-frags
__device__ short g_rgbpack[9 * 4 * 64 * 8];

__device__ __forceinline__ float leaky(float v) { return v >= 0.f ? v : 0.2f * v; }
__device__ __forceinline__ short f2b(float f) {
    __hip_bfloat16 h = __float2bfloat16(f);
    return *reinterpret_cast<short*>(&h);
}
__device__ __forceinline__ float b2f(short s) {
    return __uint_as_float(((unsigned int)(unsigned short)s) << 16);
}
__device__ __forceinline__ int swz(int col) { return ((col ^ (col >> 3)) & 7) << 3; }

__device__ __forceinline__ void uptaps(int o, int Win, int& i0, int& i1, float& w0, float& w1)
{
    int m = o >> 1;
    if ((o & 1) == 0) { i0 = m - 1; i1 = m; w0 = 0.25f; w1 = 0.75f; if (i0 < 0) { i0 = 0; w0 = 0.f; w1 = 1.f; } }
    else              { i0 = m; i1 = m + 1; w0 = 0.75f; w1 = 0.25f; if (i1 >= Win) { i1 = Win - 1; w0 = 1.f; w1 = 0.f; } }
}

// ---------------- fused prep: wpack + rgbpack + S2 ----------------
#define WPN (NLAYERS * 9 * 4 * 8 * 64)
#define RGBN (9 * 4 * 64)
#define S2N (NLAYERS * CCH * CCH)
__global__ __launch_bounds__(256) void prep_kernel(
    const float* __restrict__ convw, const float* __restrict__ rgbw)
{
    int idx = blockIdx.x * 256 + threadIdx.x;
    if (idx < WPN) {
        int lane = idx & 63;
        int cogrp = (idx >> 6) & 7;
        int chunk = (idx >> 9) & 3;
        int t = idx >> 11;
        int layer = t / 9, tap = t - layer * 9;
        int co = cogrp * 16 + (lane & 15);
        int ci0 = chunk * 32 + (lane >> 4) * 8;
        short8 v;
#pragma unroll
        for (int j = 0; j < 8; ++j)
            v[j] = f2b(convw[(((size_t)layer * CCH + co) * CCH + ci0 + j) * 9 + tap]);
        *reinterpret_cast<short8*>(&g_wpack[(size_t)idx * 8]) = v;
    } else if (idx < WPN + RGBN) {
        int u = idx - WPN;
        int lane = u & 63;
        int chunk = (u >> 6) & 3;
        int tap = u >> 8;
        int co = lane & 15;
        int ci0 = chunk * 32 + (lane >> 4) * 8;
        short8 v;
#pragma unroll
        for (int j = 0; j < 8; ++j)
            v[j] = (co < 3) ? f2b(rgbw[((size_t)(co * CCH) + ci0 + j) * 9 + tap]) : (short)0;
        *reinterpret_cast<short8*>(&g_rgbpack[(size_t)u * 8]) = v;
    } else if (idx < WPN + RGBN + S2N) {
        int u = idx - WPN - RGBN;         // [l][co][ci]
        const float* wp = convw + (size_t)u * 9;
        float s = 0.f;
#pragma unroll
        for (int t = 0; t < 9; ++t) { float m = wp[t]; s += m * m; }
        g_s2[u] = s;
    }
}

// ---------------- Mapping FC: 128 blocks/layer, 32 j x 8 k-parts, ILP-16 ----------------
// Per-thread loads: 64 (was 128) -> 4 latency rounds with 16 in flight; 2x blocks for TLP.
__global__ __launch_bounds__(256) void map_fc_kernel(
    int srcSel, int useZ, const float* __restrict__ z,
    const float* __restrict__ W, const float* __restrict__ bias)
{
    float* wout = g_w[srcSel ^ 1];
    int b = blockIdx.y;
    int jb = blockIdx.x * 32;
    int tid = threadIdx.x;
    int jl = tid & 31, kp = tid >> 5;     // kp = 0..7, each covers 64 k
    __shared__ float xin[D];
    __shared__ float part[8][32];
    __shared__ float wred[4];
    if (useZ) {
        xin[tid] = z[b * D + tid];
        xin[tid + 256] = z[b * D + tid + 256];
    } else {
        const float* win = g_w[srcSel];
        xin[tid] = win[b * D + tid];
        xin[tid + 256] = win[b * D + tid + 256];
    }
    __syncthreads();
    if (useZ) {
        float p = xin[tid] * xin[tid] + xin[tid + 256] * xin[tid + 256];
#pragma unroll
        for (int off = 32; off > 0; off >>= 1) p += __shfl_down(p, off, 64);
        if ((tid & 63) == 0) wred[tid >> 6] = p;
        __syncthreads();
        float ss = wred[0] + wred[1] + wred[2] + wred[3];
        float r = rsqrtf(ss * (1.f / 512.f) + 1e-8f);
        xin[tid] *= r; xin[tid + 256] *= r;
        __syncthreads();
    }
    const float* Wp = W + jb + jl;
    const int k0 = kp * 64;
    float a[16];
#pragma unroll
    for (int j = 0; j < 16; ++j) a[j] = 0.f;
#pragma unroll
    for (int k = k0; k < k0 + 64; k += 16) {
#pragma unroll
        for (int j = 0; j < 16; ++j)
            a[j] += xin[k + j] * Wp[(size_t)(k + j) * D];
    }
    float s16 = 0.f;
#pragma unroll
    for (int j = 0; j < 16; ++j) s16 += a[j];
    part[kp][jl] = s16;
    __syncthreads();
    if (tid < 32) {
        float s = bias[jb + tid];
#pragma unroll
        for (int p = 0; p < 8; ++p) s += part[p][tid];
        wout[b * D + jb + tid] = leaky(s);
    }
}

// ---------------- style + rstd for ALL layers (rstd via S2), one dispatch ----------------
__global__ __launch_bounds__(256) void style_rstd_kernel(
    const float* __restrict__ Aw, const float* __restrict__ Ab)
{
    int l = blockIdx.x + 1;        // layers 1..8
    int b = blockIdx.y;
    int tid = threadIdx.x;
    __shared__ float ws_[D];
    __shared__ float part[2][CCH];
    __shared__ float st[CCH];
    ws_[tid] = g_w[0][b * D + tid];
    ws_[tid + 256] = g_w[0][b * D + tid + 256];
    __syncthreads();
    {
        int c = tid & 127, kh = tid >> 7;
        const float* Ap = Aw + (size_t)l * D * CCH + c;
        const int k0 = kh * 256;
        float a0 = 0.f, a1 = 0.f, a2 = 0.f, a3 = 0.f, a4 = 0.f, a5 = 0.f, a6 = 0.f, a7 = 0.f;
        for (int k = k0; k < k0 + 256; k += 8) {
            a0 += ws_[k + 0] * Ap[(size_t)(k + 0) * CCH];
            a1 += ws_[k + 1] * Ap[(size_t)(k + 1) * CCH];
            a2 += ws_[k + 2] * Ap[(size_t)(k + 2) * CCH];
            a3 += ws_[k + 3] * Ap[(size_t)(k + 3) * CCH];
            a4 += ws_[k + 4] * Ap[(size_t)(k + 4) * CCH];
            a5 += ws_[k + 5] * Ap[(size_t)(k + 5) * CCH];
            a6 += ws_[k + 6] * Ap[(size_t)(k + 6) * CCH];
            a7 += ws_[k + 7] * Ap[(size_t)(k + 7) * CCH];
        }
        part[kh][c] = ((a0 + a1) + (a2 + a3)) + ((a4 + a5) + (a6 + a7));
    }
    __syncthreads();
    if (tid < CCH) {
        float s = part[0][tid] + part[1][tid] + Ab[l * CCH + tid];
        st[tid] = s;
        g_style_all[((size_t)l * BS + b) * CCH + tid] = s;
    }
    __syncthreads();
    int colid = tid >> 4, kpart = tid & 15;
#pragma unroll
    for (int co8 = 0; co8 < 8; ++co8) {
        int cout = co8 * 16 + colid;
        const float* sp = g_s2 + ((size_t)l * CCH + cout) * CCH + kpart * 8;
        float s = 0.f;
#pragma unroll
        for (int j = 0; j < 8; ++j) { float sv = st[kpart * 8 + j]; s += sv * sv * sp[j]; }
#pragma unroll
        for (int off = 8; off > 0; off >>= 1) s += __shfl_down(s, off, 16);
        if (kpart == 0) g_rstd_all[((size_t)l * BS + b) * CCH + cout] = rsqrtf(s + 1e-8f);
    }
}

// ---------------- fused conv layers 1+2 (both 8x8), one block per batch ----------------
__global__ __launch_bounds__(256) void conv8_pair_kernel(
    const float* __restrict__ noise,
    const float* __restrict__ Bw, const float* __restrict__ Bb)
{
    constexpr int W = 8, SW = 10, ROWS = 10, NS = 64, WIN = 4;
    const int b = blockIdx.x;
    const int tid = threadIdx.x;
    const int lane = tid & 63;
    const int wave = tid >> 6;
    const int wpx = wave & 1;
    const int wco = wave >> 1;

    __shared__ short xs1[ROWS * SW * CCH];
    __shared__ short xs2[ROWS * SW * CCH];
    __shared__ short sm[16 * CCH];
    __shared__ float style2_s[CCH], style3_s[CCH];

    if (tid < CCH) {
        style2_s[tid] = g_style_all[((size_t)2 * BS + b) * CCH + tid];
        style3_s[tid] = g_style_all[((size_t)3 * BS + b) * CCH + tid];
    }
    for (int u = tid; u < 16 * CCH; u += 256) {
        int c = u & 127;
        int pp = u >> 7;
        float v = leaky(noise[b * 4096 + pp] * Bw[c] + Bb[c])
                  * g_style_all[((size_t)1 * BS + b) * CCH + c];
        sm[u] = f2b(v);
    }
    for (int u = tid; u < ROWS * SW * 16; u += 256) {
        int ck = u & 15;
        int cell = u >> 4;
        int col = cell % SW;
        int rr = cell / SW;
        if (rr >= 1 && rr <= 8 && col >= 1 && col <= 8) continue;
        short8 zz = {0, 0, 0, 0, 0, 0, 0, 0};
        *reinterpret_cast<short8*>(&xs2[(((rr * SW + col) * CCH) + ck * 8) ^ swz(col)]) = zz;
    }
    __syncthreads();

    for (int u = tid; u < ROWS * SW * 16; u += 256) {
        int ck = u & 15;
        int rem = u >> 4;
        int col = rem % SW;
        int rr = rem / SW;
        int gy = rr - 1, gx = col - 1;
        short8 v = {0, 0, 0, 0, 0, 0, 0, 0};
        if (gy >= 0 && gy < W && gx >= 0 && gx < W) {
            int y0, y1, x0, x1; float wy0, wy1, wx0, wx1;
            uptaps(gy, WIN, y0, y1, wy0, wy1);
            uptaps(gx, WIN, x0, x1, wx0, wx1);
            short8 a00 = *reinterpret_cast<const short8*>(&sm[((size_t)y0 * WIN + x0) * CCH + ck * 8]);
            short8 a01 = *reinterpret_cast<const short8*>(&sm[((size_t)y0 * WIN + x1) * CCH + ck * 8]);
            short8 a10 = *reinterpret_cast<const short8*>(&sm[((size_t)y1 * WIN + x0) * CCH + ck * 8]);
            short8 a11 = *reinterpret_cast<const short8*>(&sm[((size_t)y1 * WIN + x1) * CCH + ck * 8]);
            float w00 = wy0 * wx0, w01 = wy0 * wx1, w10 = wy1 * wx0, w11 = wy1 * wx1;
#pragma unroll
            for (int j = 0; j < 8; ++j)
                v[j] = f2b(w00 * b2f(a00[j]) + w01 * b2f(a01[j])
                         + w10 * b2f(a10[j]) + w11 * b2f(a11[j]));
        }
        *reinterpret_cast<short8*>(&xs1[(((rr * SW + col) * CCH) + ck * 8) ^ swz(col)]) = v;
    }
    __syncthreads();

    int rL[2], cL[2];
#pragma unroll
    for (int pf = 0; pf < 2; ++pf) {
        int pl = (wpx * 2 + pf) * 16 + (lane & 15);
        cL[pf] = pl & (W - 1);
        rL[pf] = pl >> 3;
    }
    const int grpoff = (lane >> 4) * 8;

    // phase A: conv layer 1 -> xs2
    {
        f32x4 acc[2][4] = {};
        const short* wl = g_wpack + ((size_t)1 * 9 * 4 * 8 * 64 + (size_t)(wco * 4) * 64 + lane) * 8;
        short8 wc0 = *reinterpret_cast<const short8*>(wl);
        short8 wc1 = *reinterpret_cast<const short8*>(wl + 512);
        short8 wc2 = *reinterpret_cast<const short8*>(wl + 1024);
        short8 wc3 = *reinterpret_cast<const short8*>(wl + 1536);
#pragma unroll
        for (int k = 0; k < 36; ++k) {
            short8 wn0 = wc0, wn1 = wc1, wn2 = wc2, wn3 = wc3;
            if (k + 1 < 36) {
                const short* wk = wl + (size_t)(k + 1) * 4096;
                wn0 = *reinterpret_cast<const short8*>(wk);
                wn1 = *reinterpret_cast<const short8*>(wk + 512);
                wn2 = *reinterpret_cast<const short8*>(wk + 1024);
                wn3 = *reinterpret_cast<const short8*>(wk + 1536);
            }
            const int tap = k >> 2, ch = k & 3;
            const int ky = tap / 3, kx = tap - ky * 3;
#pragma unroll
            for (int pf = 0; pf < 2; ++pf) {
                int col = cL[pf] + kx;
                int idx = (((rL[pf] + ky) * SW + col) * CCH + (ch << 5) + grpoff) ^ swz(col);
                short8 xf = *reinterpret_cast<const short8*>(&xs1[idx]);
                acc[pf][0] = __builtin_amdgcn_mfma_f32_16x16x32_bf16(wc0, xf, acc[pf][0], 0, 0, 0);
                acc[pf][1] = __builtin_amdgcn_mfma_f32_16x16x32_bf16(wc1, xf, acc[pf][1], 0, 0, 0);
                acc[pf][2] = __builtin_amdgcn_mfma_f32_16x16x32_bf16(wc2, xf, acc[pf][2], 0, 0, 0);
                acc[pf][3] = __builtin_amdgcn_mfma_f32_16x16x32_bf16(wc3, xf, acc[pf][3], 0, 0, 0);
            }
            wc0 = wn0; wc1 = wn1; wc2 = wn2; wc3 = wn3;
        }
        float nz[2];
#pragma unroll
        for (int pf = 0; pf < 2; ++pf)
            nz[pf] = noise[(size_t)BS * 4096 + b * 4096 + (wpx * 2 + pf) * 16 + (lane & 15)];
#pragma unroll
        for (int cf = 0; cf < 4; ++cf) {
            const int coB = (wco * 4 + cf) * 16 + (lane >> 4) * 4;
            float rs[4], bw[4], bb[4], sn[4];
#pragma unroll
            for (int r = 0; r < 4; ++r) {
                rs[r] = g_rstd_all[((size_t)1 * BS + b) * CCH + coB + r];
                bw[r] = Bw[1 * CCH + coB + r];
                bb[r] = Bb[1 * CCH + coB + r];
                sn[r] = style2_s[coB + r];
            }
#pragma unroll
            for (int pf = 0; pf < 2; ++pf) {
                int px = (wpx * 2 + pf) * 16 + (lane & 15);
                int y = px >> 3, x = px & 7;
                short4v o;
#pragma unroll
                for (int r = 0; r < 4; ++r)
                    o[r] = f2b(leaky(acc[pf][cf][r] * rs[r] + nz[pf] * bw[r] + bb[r]) * sn[r]);
                int col = x + 1;
                *reinterpret_cast<short4v*>(&xs2[((((y + 1) * SW + col) * CCH) + coB) ^ swz(col)]) = o;
            }
        }
    }
    __syncthreads();

    // phase B: conv layer 2 -> global
    {
        f32x4 acc[2][4] = {};
        const short* wl = g_wpack + ((size_t)2 * 9 * 4 * 8 * 64 + (size_t)(wco * 4) * 64 + lane) * 8;
        short8 wc0 = *reinterpret_cast<const short8*>(wl);
        short8 wc1 = *reinterpret_cast<const short8*>(wl + 512);
        short8 wc2 = *reinterpret_cast<const short8*>(wl + 1024);
        short8 wc3 = *reinterpret_cast<const short8*>(wl + 1536);
#pragma unroll
        for (int k = 0; k < 36; ++k) {
            short8 wn0 = wc0, wn1 = wc1, wn2 = wc2, wn3 = wc3;
            if (k + 1 < 36) {
                const short* wk = wl + (size_t)(k + 1) * 4096;
                wn0 = *reinterpret_cast<const short8*>(wk);
                wn1 = *reinterpret_cast<const short8*>(wk + 512);
                wn2 = *reinterpret_cast<const short8*>(wk + 1024);
                wn3 = *reinterpret_cast<const short8*>(wk + 1536);
            }
            const int tap = k >> 2, ch = k & 3;
            const int ky = tap / 3, kx = tap - ky * 3;
#pragma unroll
            for (int pf = 0; pf < 2; ++pf) {
                int col = cL[pf] + kx;
                int idx = (((rL[pf] + ky) * SW + col) * CCH + (ch << 5) + grpoff) ^ swz(col);
                short8 xf = *reinterpret_cast<const short8*>(&xs2[idx]);
                acc[pf][0] = __builtin_amdgcn_mfma_f32_16x16x32_bf16(wc0, xf, acc[pf][0], 0, 0, 0);
                acc[pf][1] = __builtin_amdgcn_mfma_f32_16x16x32_bf16(wc1, xf, acc[pf][1], 0, 0, 0);
                acc[pf][2] = __builtin_amdgcn_mfma_f32_16x16x32_bf16(wc2, xf, acc[pf][2], 0, 0, 0);
                acc[pf][3] = __builtin_amdgcn_mfma_f32_16x16x32_bf16(wc3, xf, acc[pf][3], 0, 0, 0);
            }
            wc0 = wn0; wc1 = wn1; wc2 = wn2; wc3 = wn3;
        }
        float nz[2];
#pragma unroll
        for (int pf = 0; pf < 2; ++pf)
            nz[pf] = noise[(size_t)2 * BS * 4096 + b * 4096 + (wpx * 2 + pf) * 16 + (lane & 15)];
#pragma unroll
        for (int cf = 0; cf < 4; ++cf) {
            const int coB = (wco * 4 + cf) * 16 + (lane >> 4) * 4;
            float rs[4], bw[4], bb[4], sn[4];
#pragma unroll
            for (int r = 0; r < 4; ++r) {
                rs[r] = g_rstd_all[((size_t)2 * BS + b) * CCH + coB + r];
                bw[r] = Bw[2 * CCH + coB + r];
                bb[r] = Bb[2 * CCH + coB + r];
                sn[r] = style3_s[coB + r];
            }
#pragma unroll
            for (int pf = 0; pf < 2; ++pf) {
                int px = (wpx * 2 + pf) * 16 + (lane & 15);
                short4v o;
#pragma unroll
                for (int r = 0; r < 4; ++r)
                    o[r] = f2b(leaky(acc[pf][cf][r] * rs[r] + nz[pf] * bw[r] + bb[r]) * sn[r]);
                *reinterpret_cast<short4v*>(&g_bufA[((size_t)b * NS + px) * CCH + coB]) = o;
            }
        }
    }
}

// ---------------- MFMA modulated conv (NHWC bf16), layers 3..8 ----------------
// Tile = TW x TH px (TW*TH = 64), TLW = log2(TW). Block covers 128 co; 4 waves
// = 2 px-halves x 2 co-halves (2 pf x 4 cf each). UPM: 0 plain, 1 fused upsample.
template<int LW, int UPM, int TLW>
__global__ __launch_bounds__(256) void conv_mfma_kernel(
    int srcSel, int layer, int layerNext,
    const float* __restrict__ noise,
    const float* __restrict__ Bw, const float* __restrict__ Bb)
{
    constexpr int W = 1 << LW;
    constexpr int TW = 1 << TLW;
    constexpr int TH = 64 >> TLW;
    constexpr int SW = TW + 2;
    constexpr int ROWS = TH + 2;
    constexpr int NS = W * W;
    constexpr int WIN = W / 2;
    constexpr int TILES_X = W / TW;

    const short* xin = srcSel ? g_bufB : g_bufA;
    short* xout = srcSel ? g_bufA : g_bufB;

    const int b = blockIdx.y;
    const int tx = blockIdx.x & (TILES_X - 1);
    const int ty = blockIdx.x >> (LW - TLW);
    const int rowBase = ty * TH;
    const int colBase = tx * TW;
    const int tid = threadIdx.x;
    const int lane = tid & 63;
    const int wave = tid >> 6;
    const int wpx = wave & 1;
    const int wco = wave >> 1;

    __shared__ short xs[ROWS * SW * CCH];
    __shared__ float style_s[CCH];

    if (tid < CCH)
        style_s[tid] = layerNext ? g_style_all[((size_t)layerNext * BS + b) * CCH + tid] : 1.f;

    {
        const short* src = xin + (size_t)b * NS * CCH;
        const short* srcH = xin + (size_t)b * WIN * WIN * CCH;
        constexpr int UN = ROWS * SW * 16;
        for (int u = tid; u < UN; u += 256) {
            int ck = u & 15;
            int rem = u >> 4;
            int col = rem % SW;
            int rr = rem / SW;
            int gy = rowBase + rr - 1, gx = colBase + col - 1;
            short8 v = {0, 0, 0, 0, 0, 0, 0, 0};
            if (gy >= 0 && gy < W && gx >= 0 && gx < W) {
                if (UPM == 0) {
                    v = *reinterpret_cast<const short8*>(&src[((size_t)gy * W + gx) * CCH + ck * 8]);
                } else {
                    int y0, y1, x0, x1; float wy0, wy1, wx0, wx1;
                    uptaps(gy, WIN, y0, y1, wy0, wy1);
                    uptaps(gx, WIN, x0, x1, wx0, wx1);
                    short8 a00 = *reinterpret_cast<const short8*>(&srcH[((size_t)y0 * WIN + x0) * CCH + ck * 8]);
                    short8 a01 = *reinterpret_cast<const short8*>(&srcH[((size_t)y0 * WIN + x1) * CCH + ck * 8]);
                    short8 a10 = *reinterpret_cast<const short8*>(&srcH[((size_t)y1 * WIN + x0) * CCH + ck * 8]);
                    short8 a11 = *reinterpret_cast<const short8*>(&srcH[((size_t)y1 * WIN + x1) * CCH + ck * 8]);
                    float w00 = wy0 * wx0, w01 = wy0 * wx1, w10 = wy1 * wx0, w11 = wy1 * wx1;
#pragma unroll
                    for (int j = 0; j < 8; ++j)
                        v[j] = f2b(w00 * b2f(a00[j]) + w01 * b2f(a01[j])
                                 + w10 * b2f(a10[j]) + w11 * b2f(a11[j]));
                }
            }
            *reinterpret_cast<short8*>(&xs[(((rr * SW + col) * CCH) + ck * 8) ^ swz(col)]) = v;
        }
    }
    __syncthreads();

    int rL[2], cL[2];
#pragma unroll
    for (int pf = 0; pf < 2; ++pf) {
        int pl = (wpx * 2 + pf) * 16 + (lane & 15);
        cL[pf] = pl & (TW - 1);
        rL[pf] = pl >> TLW;
    }
    const int grpoff = (lane >> 4) * 8;

    f32x4 acc[2][4] = {};
    const short* wl = g_wpack + ((size_t)layer * 9 * 4 * 8 * 64
                                 + (size_t)(wco * 4) * 64 + lane) * 8;

    short8 wc0 = *reinterpret_cast<const short8*>(wl);
    short8 wc1 = *reinterpret_cast<const short8*>(wl + 512);
    short8 wc2 = *reinterpret_cast<const short8*>(wl + 1024);
    short8 wc3 = *reinterpret_cast<const short8*>(wl + 1536);
#pragma unroll
    for (int k = 0; k < 36; ++k) {
        short8 wn0 = wc0, wn1 = wc1, wn2 = wc2, wn3 = wc3;
        if (k + 1 < 36) {
            const short* wk = wl + (size_t)(k + 1) * 4096;
            wn0 = *reinterpret_cast<const short8*>(wk);
            wn1 = *reinterpret_cast<const short8*>(wk + 512);
            wn2 = *reinterpret_cast<const short8*>(wk + 1024);
            wn3 = *reinterpret_cast<const short8*>(wk + 1536);
        }
        const int tap = k >> 2, ch = k & 3;
        const int ky = tap / 3, kx = tap - ky * 3;
#pragma unroll
        for (int pf = 0; pf < 2; ++pf) {
            int col = cL[pf] + kx;
            int idx = (((rL[pf] + ky) * SW + col) * CCH + (ch << 5) + grpoff) ^ swz(col);
            short8 xf = *reinterpret_cast<const short8*>(&xs[idx]);
            acc[pf][0] = __builtin_amdgcn_mfma_f32_16x16x32_bf16(wc0, xf, acc[pf][0], 0, 0, 0);
            acc[pf][1] = __builtin_amdgcn_mfma_f32_16x16x32_bf16(wc1, xf, acc[pf][1], 0, 0, 0);
            acc[pf][2] = __builtin_amdgcn_mfma_f32_16x16x32_bf16(wc2, xf, acc[pf][2], 0, 0, 0);
            acc[pf][3] = __builtin_amdgcn_mfma_f32_16x16x32_bf16(wc3, xf, acc[pf][3], 0, 0, 0);
        }
        wc0 = wn0; wc1 = wn1; wc2 = wn2; wc3 = wn3;
    }

    float nz[2];
    int pxg[2];
#pragma unroll
    for (int pf = 0; pf < 2; ++pf) {
        int pl = (wpx * 2 + pf) * 16 + (lane & 15);
        int x = pl & (TW - 1), y = pl >> TLW;
        pxg[pf] = (rowBase + y) * W + colBase + x;
        nz[pf] = noise[b * 4096 + pxg[pf]];
    }
#pragma unroll
    for (int cf = 0; cf < 4; ++cf) {
        const int coB = (wco * 4 + cf) * 16 + (lane >> 4) * 4;
        float rs[4], bw[4], bb[4], sn[4];
#pragma unroll
        for (int r = 0; r < 4; ++r) {
            rs[r] = g_rstd_all[((size_t)layer * BS + b) * CCH + coB + r];
            bw[r] = Bw[coB + r];
            bb[r] = Bb[coB + r];
            sn[r] = style_s[coB + r];
        }
#pragma unroll
        for (int pf = 0; pf < 2; ++pf) {
            short4v o;
#pragma unroll
            for (int r = 0; r < 4; ++r) {
                float v = leaky(acc[pf][cf][r] * rs[r] + nz[pf] * bw[r] + bb[r]) * sn[r];
                o[r] = f2b(v);
            }
            *reinterpret_cast<short4v*>(&xout[((size_t)b * NS + pxg[pf]) * CCH + coB]) = o;
        }
    }
}

// ---------------- MFMA toRGB (W=64; 32x2 tiles; 3 real rows in 16-row M; waves split K) ----------------
__global__ __launch_bounds__(256) void rgb_mfma_kernel(
    int srcSel, const float* __restrict__ rgbb, float* __restrict__ out)
{
    constexpr int W = 64, TW = 32, TH = 2, SW = 34, ROWS = 4, NS = 4096;
    const short* xin = srcSel ? g_bufB : g_bufA;

    const int b = blockIdx.y;
    const int tx = blockIdx.x & 1;
    const int ty = blockIdx.x >> 1;
    const int rowBase = ty * TH;
    const int colBase = tx * TW;
    const int tid = threadIdx.x;
    const int lane = tid & 63;
    const int wave = tid >> 6;     // K-chunk

    __shared__ short xs[ROWS * SW * CCH];

    {
        const short* src = xin + (size_t)b * NS * CCH;
        constexpr int UN = ROWS * SW * 16;
        for (int u = tid; u < UN; u += 256) {
            int ck = u & 15;
            int rem = u >> 4;
            int col = rem % SW;
            int rr = rem / SW;
            int gy = rowBase + rr - 1, gx = colBase + col - 1;
            short8 v = {0, 0, 0, 0, 0, 0, 0, 0};
            if (gy >= 0 && gy < W && gx >= 0 && gx < W)
                v = *reinterpret_cast<const short8*>(&src[((size_t)gy * W + gx) * CCH + ck * 8]);
            *reinterpret_cast<short8*>(&xs[(((rr * SW + col) * CCH) + ck * 8) ^ swz(col)]) = v;
        }
    }
    __syncthreads();

    const int grpoff = (lane >> 4) * 8;
    const int cl = lane & 15;
    f32x4 acc[4] = {};
#pragma unroll
    for (int tap = 0; tap < 9; ++tap) {
        const int ky = tap / 3, kx = tap - ky * 3;
        short8 wf = *reinterpret_cast<const short8*>(
            &g_rgbpack[((size_t)(tap * 4 + wave) * 64 + lane) * 8]);
#pragma unroll
        for (int pf = 0; pf < 4; ++pf) {
            int pl = pf * 16 + cl;
            int x = pl & (TW - 1), y = pl >> 5;
            int col = x + kx;
            int idx = (((y + ky) * SW + col) * CCH + (wave << 5) + grpoff) ^ swz(col);
            short8 xf = *reinterpret_cast<const short8*>(&xs[idx]);
            acc[pf] = __builtin_amdgcn_mfma_f32_16x16x32_bf16(wf, xf, acc[pf], 0, 0, 0);
        }
    }
    __syncthreads();
    float* red = reinterpret_cast<float*>(xs);
    if (wave > 0) {
#pragma unroll
        for (int pf = 0; pf < 4; ++pf)
#pragma unroll
            for (int r = 0; r < 4; ++r)
                red[(((wave - 1) * 4 + pf) * 64 + lane) * 4 + r] = acc[pf][r];
    }
    __syncthreads();
    if (wave == 0 && (lane >> 4) == 0) {
#pragma unroll
        for (int pf = 0; pf < 4; ++pf) {
            int pl = pf * 16 + cl;
            int x = pl & (TW - 1), y = pl >> 5;
            int px = (rowBase + y) * W + colBase + x;
#pragma unroll
            for (int r = 0; r < 3; ++r) {
                float s = acc[pf][r];
#pragma unroll
                for (int wv = 0; wv < 3; ++wv)
                    s += red[((wv * 4 + pf) * 64 + lane) * 4 + r];
                out[(size_t)(b * 3 + r) * NS + px] = s + rgbb[r];
            }
        }
    }
}

// ---------------- launch ----------------
extern "C" void kernel_launch(void* const* d_in, const int* in_sizes, int n_in,
                              void* d_out, int out_size, void* d_ws, size_t ws_size,
                              hipStream_t stream)
{
    const float* latent = (const float*)d_in[0];
    const float* noise  = (const float*)d_in[1];
    const float* map_w  = (const float*)d_in[2];
    const float* map_b  = (const float*)d_in[3];
    const float* A_w    = (const float*)d_in[4];
    const float* A_b    = (const float*)d_in[5];
    const float* B_w    = (const float*)d_in[6];
    const float* B_b    = (const float*)d_in[7];
    const float* conv_w = (const float*)d_in[8];
    const float* rgb_w  = (const float*)d_in[9];
    const float* rgb_b  = (const float*)d_in[10];
    float* out = (float*)d_out;
    (void)d_ws; (void)ws_size;

    prep_kernel<<<(WPN + RGBN + S2N + 255) / 256, 256, 0, stream>>>(conv_w, rgb_w);

    // mapping: 8 dispatches, 128 blocks each (16 j-tiles x BS), pixelnorm fused in layer 0
    int wsel = 0;
    for (int i = 0; i < LMAP; ++i) {
        map_fc_kernel<<<dim3(16, BS), 256, 0, stream>>>(
            wsel, i == 0 ? 1 : 0, latent, map_w + (size_t)i * D * D, map_b + i * D);
        wsel ^= 1;
    }

    style_rstd_kernel<<<dim3(8, BS), 256, 0, stream>>>(A_w, A_b);

    // layers 1+2 fused (8x8) -> g_bufA
    conv8_pair_kernel<<<BS, 256, 0, stream>>>(noise, B_w, B_b);

    int cur = 0;   // data in g_bufA
    int Hc = 8;
    for (int i = 3; i < NLAYERS; ++i) {
        if (i & 1) Hc *= 2;
        int ns = Hc * Hc;
        int lnext = (i < 8) ? (i + 1) : 0;
        dim3 grid(ns / 64, BS);
        const float* nz = noise + (size_t)i * BS * 4096;
        switch (i) {
            case 3: conv_mfma_kernel<4, 1, 4><<<grid, 256, 0, stream>>>(cur, i, lnext, nz, B_w + i * CCH, B_b + i * CCH); break;
            case 4: conv_mfma_kernel<4, 0, 4><<<grid, 256, 0, stream>>>(cur, i, lnext, nz, B_w + i * CCH, B_b + i * CCH); break;
            case 5: conv_mfma_kernel<5, 1, 5><<<grid, 256, 0, stream>>>(cur, i, lnext, nz, B_w + i * CCH, B_b + i * CCH); break;
            case 6: conv_mfma_kernel<5, 0, 5><<<grid, 256, 0, stream>>>(cur, i, lnext, nz, B_w + i * CCH, B_b + i * CCH); break;
            case 7: conv_mfma_kernel<6, 1, 5><<<grid, 256, 0, stream>>>(cur, i, lnext, nz, B_w + i * CCH, B_b + i * CCH); break;
            case 8: conv_mfma_kernel<6, 0, 5><<<grid, 256, 0, stream>>>(cur, i, lnext, nz, B_w + i * CCH, B_b + i * CCH); break;
        }
        cur ^= 1;
    }

    rgb_mfma_kernel<<<dim3(64, BS), 256, 0, stream>>>(cur, rgb_b, out);
}

// Round 16
// 194.865 us; speedup vs baseline: 1.2364x; 1.0229x over previous
//
#include <hip/hip_runtime.h>
#include <hip/hip_bf16.h>

#define BS 8
#define D 512
#define CCH 128
#define LMAP 8
#define NLAYERS 9

typedef short short8 __attribute__((ext_vector_type(8)));
typedef short short4v __attribute__((ext_vector_type(4)));
typedef float f32x4 __attribute__((ext_vector_type(4)));

// ---- module-global scratch ----
__device__ short g_bufA[(size_t)BS * 4096 * CCH];   // bf16 NHWC [b][px][ci]
__device__ short g_bufB[(size_t)BS * 4096 * CCH];
__device__ float g_w[2][BS * D];
__device__ float g_style_all[NLAYERS * BS * CCH];
__device__ float g_rstd_all[NLAYERS * BS * CCH];
__device__ float g_s2[(size_t)NLAYERS * CCH * CCH];              // S2[l][co][ci] = sum_tap w^2
__device__ short g_wpack[(size_t)NLAYERS * 9 * 4 * 8 * 64 * 8];  // packed bf16 W-frags
__device__ short g_rgbpack[9 * 4 * 64 * 8];

__device__ __forceinline__ float leaky(float v) { return v >= 0.f ? v : 0.2f * v; }
__device__ __forceinline__ short f2b(float f) {
    __hip_bfloat16 h = __float2bfloat16(f);
    return *reinterpret_cast<short*>(&h);
}
__device__ __forceinline__ float b2f(short s) {
    return __uint_as_float(((unsigned int)(unsigned short)s) << 16);
}
__device__ __forceinline__ int swz(int col) { return ((col ^ (col >> 3)) & 7) << 3; }

__device__ __forceinline__ void uptaps(int o, int Win, int& i0, int& i1, float& w0, float& w1)
{
    int m = o >> 1;
    if ((o & 1) == 0) { i0 = m - 1; i1 = m; w0 = 0.25f; w1 = 0.75f; if (i0 < 0) { i0 = 0; w0 = 0.f; w1 = 1.f; } }
    else              { i0 = m; i1 = m + 1; w0 = 0.75f; w1 = 0.25f; if (i1 >= Win) { i1 = Win - 1; w0 = 1.f; w1 = 0.f; } }
}

#define WPN (NLAYERS * 9 * 4 * 8 * 64)
#define RGBN (9 * 4 * 64)
#define S2N (NLAYERS * CCH * CCH)
#define NPREPB ((WPN + RGBN + S2N + 255) / 256)
#define NMAPB (32 * BS)

// ---------------- fused: map layer 0 (pixelnorm + FC0, blocks 0..255) + prep (rest) ----------------
__global__ __launch_bounds__(256) void prep_map0_kernel(
    const float* __restrict__ z, const float* __restrict__ W0, const float* __restrict__ b0,
    const float* __restrict__ convw, const float* __restrict__ rgbw)
{
    const int bid = blockIdx.x;
    const int tid = threadIdx.x;
    if (bid < NMAPB) {
        // ---- mapping layer 0: jt = bid&31 (16 j each), b = bid>>5 ----
        const int jt = bid & 31, b = bid >> 5;
        const int jb = jt * 16;
        const int jl = tid & 15, kp = tid >> 4;       // 16 kp x 32 k
        __shared__ float xin[D];
        __shared__ float part[16][16];
        __shared__ float wred[4];
        xin[tid] = z[b * D + tid];
        xin[tid + 256] = z[b * D + tid + 256];
        __syncthreads();
        {
            float p = xin[tid] * xin[tid] + xin[tid + 256] * xin[tid + 256];
#pragma unroll
            for (int off = 32; off > 0; off >>= 1) p += __shfl_down(p, off, 64);
            if ((tid & 63) == 0) wred[tid >> 6] = p;
            __syncthreads();
            float ss = wred[0] + wred[1] + wred[2] + wred[3];
            float r = rsqrtf(ss * (1.f / 512.f) + 1e-8f);
            xin[tid] *= r; xin[tid + 256] *= r;
            __syncthreads();
        }
        const float* Wp = W0 + jb + jl;
        const int k0 = kp * 32;
        float a[16];
#pragma unroll
        for (int j = 0; j < 16; ++j) a[j] = 0.f;
#pragma unroll
        for (int k = k0; k < k0 + 32; k += 16) {
#pragma unroll
            for (int j = 0; j < 16; ++j)
                a[j] += xin[k + j] * Wp[(size_t)(k + j) * D];
        }
        float s16 = 0.f;
#pragma unroll
        for (int j = 0; j < 16; ++j) s16 += a[j];
        part[kp][jl] = s16;
        __syncthreads();
        if (tid < 16) {
            float s = b0[jb + tid];
#pragma unroll
            for (int p = 0; p < 16; ++p) s += part[p][tid];
            g_w[1][b * D + jb + tid] = leaky(s);
        }
        return;
    }
    // ---- prep work ----
    int idx = (bid - NMAPB) * 256 + tid;
    if (idx < WPN) {
        int lane = idx & 63;
        int cogrp = (idx >> 6) & 7;
        int chunk = (idx >> 9) & 3;
        int t = idx >> 11;
        int layer = t / 9, tap = t - layer * 9;
        int co = cogrp * 16 + (lane & 15);
        int ci0 = chunk * 32 + (lane >> 4) * 8;
        short8 v;
#pragma unroll
        for (int j = 0; j < 8; ++j)
            v[j] = f2b(convw[(((size_t)layer * CCH + co) * CCH + ci0 + j) * 9 + tap]);
        *reinterpret_cast<short8*>(&g_wpack[(size_t)idx * 8]) = v;
    } else if (idx < WPN + RGBN) {
        int u = idx - WPN;
        int lane = u & 63;
        int chunk = (u >> 6) & 3;
        int tap = u >> 8;
        int co = lane & 15;
        int ci0 = chunk * 32 + (lane >> 4) * 8;
        short8 v;
#pragma unroll
        for (int j = 0; j < 8; ++j)
            v[j] = (co < 3) ? f2b(rgbw[((size_t)(co * CCH) + ci0 + j) * 9 + tap]) : (short)0;
        *reinterpret_cast<short8*>(&g_rgbpack[(size_t)u * 8]) = v;
    } else if (idx < WPN + RGBN + S2N) {
        int u = idx - WPN - RGBN;         // [l][co][ci]
        const float* wp = convw + (size_t)u * 9;
        float s = 0.f;
#pragma unroll
        for (int t = 0; t < 9; ++t) { float m = wp[t]; s += m * m; }
        g_s2[u] = s;
    }
}

// ---------------- Mapping FC layers 1..7: 256 blocks/layer, 16 j x 16 k-parts, ILP-16 ----------------
__global__ __launch_bounds__(256) void map_fc_kernel(
    int srcSel, const float* __restrict__ W, const float* __restrict__ bias)
{
    float* wout = g_w[srcSel ^ 1];
    int b = blockIdx.y;
    int jb = blockIdx.x * 16;
    int tid = threadIdx.x;
    int jl = tid & 15, kp = tid >> 4;     // 16 kp, each covers 32 k
    __shared__ float xin[D];
    __shared__ float part[16][16];
    const float* win = g_w[srcSel];
    xin[tid] = win[b * D + tid];
    xin[tid + 256] = win[b * D + tid + 256];
    __syncthreads();
    const float* Wp = W + jb + jl;
    const int k0 = kp * 32;
    float a[16];
#pragma unroll
    for (int j = 0; j < 16; ++j) a[j] = 0.f;
#pragma unroll
    for (int k = k0; k < k0 + 32; k += 16) {
#pragma unroll
        for (int j = 0; j < 16; ++j)
            a[j] += xin[k + j] * Wp[(size_t)(k + j) * D];
    }
    float s16 = 0.f;
#pragma unroll
    for (int j = 0; j < 16; ++j) s16 += a[j];
    part[kp][jl] = s16;
    __syncthreads();
    if (tid < 16) {
        float s = bias[jb + tid];
#pragma unroll
        for (int p = 0; p < 16; ++p) s += part[p][tid];
        wout[b * D + jb + tid] = leaky(s);
    }
}

// ---------------- style + rstd for ALL layers (rstd via S2), one dispatch ----------------
__global__ __launch_bounds__(256) void style_rstd_kernel(
    const float* __restrict__ Aw, const float* __restrict__ Ab)
{
    int l = blockIdx.x + 1;        // layers 1..8
    int b = blockIdx.y;
    int tid = threadIdx.x;
    __shared__ float ws_[D];
    __shared__ float part[2][CCH];
    __shared__ float st[CCH];
    ws_[tid] = g_w[0][b * D + tid];
    ws_[tid + 256] = g_w[0][b * D + tid + 256];
    __syncthreads();
    {
        int c = tid & 127, kh = tid >> 7;
        const float* Ap = Aw + (size_t)l * D * CCH + c;
        const int k0 = kh * 256;
        float a0 = 0.f, a1 = 0.f, a2 = 0.f, a3 = 0.f, a4 = 0.f, a5 = 0.f, a6 = 0.f, a7 = 0.f;
        for (int k = k0; k < k0 + 256; k += 8) {
            a0 += ws_[k + 0] * Ap[(size_t)(k + 0) * CCH];
            a1 += ws_[k + 1] * Ap[(size_t)(k + 1) * CCH];
            a2 += ws_[k + 2] * Ap[(size_t)(k + 2) * CCH];
            a3 += ws_[k + 3] * Ap[(size_t)(k + 3) * CCH];
            a4 += ws_[k + 4] * Ap[(size_t)(k + 4) * CCH];
            a5 += ws_[k + 5] * Ap[(size_t)(k + 5) * CCH];
            a6 += ws_[k + 6] * Ap[(size_t)(k + 6) * CCH];
            a7 += ws_[k + 7] * Ap[(size_t)(k + 7) * CCH];
        }
        part[kh][c] = ((a0 + a1) + (a2 + a3)) + ((a4 + a5) + (a6 + a7));
    }
    __syncthreads();
    if (tid < CCH) {
        float s = part[0][tid] + part[1][tid] + Ab[l * CCH + tid];
        st[tid] = s;
        g_style_all[((size_t)l * BS + b) * CCH + tid] = s;
    }
    __syncthreads();
    int colid = tid >> 4, kpart = tid & 15;
#pragma unroll
    for (int co8 = 0; co8 < 8; ++co8) {
        int cout = co8 * 16 + colid;
        const float* sp = g_s2 + ((size_t)l * CCH + cout) * CCH + kpart * 8;
        float s = 0.f;
#pragma unroll
        for (int j = 0; j < 8; ++j) { float sv = st[kpart * 8 + j]; s += sv * sv * sp[j]; }
#pragma unroll
        for (int off = 8; off > 0; off >>= 1) s += __shfl_down(s, off, 16);
        if (kpart == 0) g_rstd_all[((size_t)l * BS + b) * CCH + cout] = rsqrtf(s + 1e-8f);
    }
}

// ---------------- fused conv layers 1+2 (both 8x8), one block per batch ----------------
__global__ __launch_bounds__(256) void conv8_pair_kernel(
    const float* __restrict__ noise,
    const float* __restrict__ Bw, const float* __restrict__ Bb)
{
    constexpr int W = 8, SW = 10, ROWS = 10, NS = 64, WIN = 4;
    const int b = blockIdx.x;
    const int tid = threadIdx.x;
    const int lane = tid & 63;
    const int wave = tid >> 6;
    const int wpx = wave & 1;
    const int wco = wave >> 1;

    __shared__ short xs1[ROWS * SW * CCH];
    __shared__ short xs2[ROWS * SW * CCH];
    __shared__ short sm[16 * CCH];
    __shared__ float style2_s[CCH], style3_s[CCH];

    if (tid < CCH) {
        style2_s[tid] = g_style_all[((size_t)2 * BS + b) * CCH + tid];
        style3_s[tid] = g_style_all[((size_t)3 * BS + b) * CCH + tid];
    }
    for (int u = tid; u < 16 * CCH; u += 256) {
        int c = u & 127;
        int pp = u >> 7;
        float v = leaky(noise[b * 4096 + pp] * Bw[c] + Bb[c])
                  * g_style_all[((size_t)1 * BS + b) * CCH + c];
        sm[u] = f2b(v);
    }
    for (int u = tid; u < ROWS * SW * 16; u += 256) {
        int ck = u & 15;
        int cell = u >> 4;
        int col = cell % SW;
        int rr = cell / SW;
        if (rr >= 1 && rr <= 8 && col >= 1 && col <= 8) continue;
        short8 zz = {0, 0, 0, 0, 0, 0, 0, 0};
        *reinterpret_cast<short8*>(&xs2[(((rr * SW + col) * CCH) + ck * 8) ^ swz(col)]) = zz;
    }
    __syncthreads();

    for (int u = tid; u < ROWS * SW * 16; u += 256) {
        int ck = u & 15;
        int rem = u >> 4;
        int col = rem % SW;
        int rr = rem / SW;
        int gy = rr - 1, gx = col - 1;
        short8 v = {0, 0, 0, 0, 0, 0, 0, 0};
        if (gy >= 0 && gy < W && gx >= 0 && gx < W) {
            int y0, y1, x0, x1; float wy0, wy1, wx0, wx1;
            uptaps(gy, WIN, y0, y1, wy0, wy1);
            uptaps(gx, WIN, x0, x1, wx0, wx1);
            short8 a00 = *reinterpret_cast<const short8*>(&sm[((size_t)y0 * WIN + x0) * CCH + ck * 8]);
            short8 a01 = *reinterpret_cast<const short8*>(&sm[((size_t)y0 * WIN + x1) * CCH + ck * 8]);
            short8 a10 = *reinterpret_cast<const short8*>(&sm[((size_t)y1 * WIN + x0) * CCH + ck * 8]);
            short8 a11 = *reinterpret_cast<const short8*>(&sm[((size_t)y1 * WIN + x1) * CCH + ck * 8]);
            float w00 = wy0 * wx0, w01 = wy0 * wx1, w10 = wy1 * wx0, w11 = wy1 * wx1;
#pragma unroll
            for (int j = 0; j < 8; ++j)
                v[j] = f2b(w00 * b2f(a00[j]) + w01 * b2f(a01[j])
                         + w10 * b2f(a10[j]) + w11 * b2f(a11[j]));
        }
        *reinterpret_cast<short8*>(&xs1[(((rr * SW + col) * CCH) + ck * 8) ^ swz(col)]) = v;
    }
    __syncthreads();

    int rL[2], cL[2];
#pragma unroll
    for (int pf = 0; pf < 2; ++pf) {
        int pl = (wpx * 2 + pf) * 16 + (lane & 15);
        cL[pf] = pl & (W - 1);
        rL[pf] = pl >> 3;
    }
    const int grpoff = (lane >> 4) * 8;

    // phase A: conv layer 1 -> xs2
    {
        f32x4 acc[2][4] = {};
        const short* wl = g_wpack + ((size_t)1 * 9 * 4 * 8 * 64 + (size_t)(wco * 4) * 64 + lane) * 8;
        short8 wc0 = *reinterpret_cast<const short8*>(wl);
        short8 wc1 = *reinterpret_cast<const short8*>(wl + 512);
        short8 wc2 = *reinterpret_cast<const short8*>(wl + 1024);
        short8 wc3 = *reinterpret_cast<const short8*>(wl + 1536);
#pragma unroll
        for (int k = 0; k < 36; ++k) {
            short8 wn0 = wc0, wn1 = wc1, wn2 = wc2, wn3 = wc3;
            if (k + 1 < 36) {
                const short* wk = wl + (size_t)(k + 1) * 4096;
                wn0 = *reinterpret_cast<const short8*>(wk);
                wn1 = *reinterpret_cast<const short8*>(wk + 512);
                wn2 = *reinterpret_cast<const short8*>(wk + 1024);
                wn3 = *reinterpret_cast<const short8*>(wk + 1536);
            }
            const int tap = k >> 2, ch = k & 3;
            const int ky = tap / 3, kx = tap - ky * 3;
#pragma unroll
            for (int pf = 0; pf < 2; ++pf) {
                int col = cL[pf] + kx;
                int idx = (((rL[pf] + ky) * SW + col) * CCH + (ch << 5) + grpoff) ^ swz(col);
                short8 xf = *reinterpret_cast<const short8*>(&xs1[idx]);
                acc[pf][0] = __builtin_amdgcn_mfma_f32_16x16x32_bf16(wc0, xf, acc[pf][0], 0, 0, 0);
                acc[pf][1] = __builtin_amdgcn_mfma_f32_16x16x32_bf16(wc1, xf, acc[pf][1], 0, 0, 0);
                acc[pf][2] = __builtin_amdgcn_mfma_f32_16x16x32_bf16(wc2, xf, acc[pf][2], 0, 0, 0);
                acc[pf][3] = __builtin_amdgcn_mfma_f32_16x16x32_bf16(wc3, xf, acc[pf][3], 0, 0, 0);
            }
            wc0 = wn0; wc1 = wn1; wc2 = wn2; wc3 = wn3;
        }
        float nz[2];
#pragma unroll
        for (int pf = 0; pf < 2; ++pf)
            nz[pf] = noise[(size_t)BS * 4096 + b * 4096 + (wpx * 2 + pf) * 16 + (lane & 15)];
#pragma unroll
        for (int cf = 0; cf < 4; ++cf) {
            const int coB = (wco * 4 + cf) * 16 + (lane >> 4) * 4;
            float rs[4], bw[4], bb[4], sn[4];
#pragma unroll
            for (int r = 0; r < 4; ++r) {
                rs[r] = g_rstd_all[((size_t)1 * BS + b) * CCH + coB + r];
                bw[r] = Bw[1 * CCH + coB + r];
                bb[r] = Bb[1 * CCH + coB + r];
                sn[r] = style2_s[coB + r];
            }
#pragma unroll
            for (int pf = 0; pf < 2; ++pf) {
                int px = (wpx * 2 + pf) * 16 + (lane & 15);
                int y = px >> 3, x = px & 7;
                short4v o;
#pragma unroll
                for (int r = 0; r < 4; ++r)
                    o[r] = f2b(leaky(acc[pf][cf][r] * rs[r] + nz[pf] * bw[r] + bb[r]) * sn[r]);
                int col = x + 1;
                *reinterpret_cast<short4v*>(&xs2[((((y + 1) * SW + col) * CCH) + coB) ^ swz(col)]) = o;
            }
        }
    }
    __syncthreads();

    // phase B: conv layer 2 -> global
    {
        f32x4 acc[2][4] = {};
        const short* wl = g_wpack + ((size_t)2 * 9 * 4 * 8 * 64 + (size_t)(wco * 4) * 64 + lane) * 8;
        short8 wc0 = *reinterpret_cast<const short8*>(wl);
        short8 wc1 = *reinterpret_cast<const short8*>(wl + 512);
        short8 wc2 = *reinterpret_cast<const short8*>(wl + 1024);
        short8 wc3 = *reinterpret_cast<const short8*>(wl + 1536);
#pragma unroll
        for (int k = 0; k < 36; ++k) {
            short8 wn0 = wc0, wn1 = wc1, wn2 = wc2, wn3 = wc3;
            if (k + 1 < 36) {
                const short* wk = wl + (size_t)(k + 1) * 4096;
                wn0 = *reinterpret_cast<const short8*>(wk);
                wn1 = *reinterpret_cast<const short8*>(wk + 512);
                wn2 = *reinterpret_cast<const short8*>(wk + 1024);
                wn3 = *reinterpret_cast<const short8*>(wk + 1536);
            }
            const int tap = k >> 2, ch = k & 3;
            const int ky = tap / 3, kx = tap - ky * 3;
#pragma unroll
            for (int pf = 0; pf < 2; ++pf) {
                int col = cL[pf] + kx;
                int idx = (((rL[pf] + ky) * SW + col) * CCH + (ch << 5) + grpoff) ^ swz(col);
                short8 xf = *reinterpret_cast<const short8*>(&xs2[idx]);
                acc[pf][0] = __builtin_amdgcn_mfma_f32_16x16x32_bf16(wc0, xf, acc[pf][0], 0, 0, 0);
                acc[pf][1] = __builtin_amdgcn_mfma_f32_16x16x32_bf16(wc1, xf, acc[pf][1], 0, 0, 0);
                acc[pf][2] = __builtin_amdgcn_mfma_f32_16x16x32_bf16(wc2, xf, acc[pf][2], 0, 0, 0);
                acc[pf][3] = __builtin_amdgcn_mfma_f32_16x16x32_bf16(wc3, xf, acc[pf][3], 0, 0, 0);
            }
            wc0 = wn0; wc1 = wn1; wc2 = wn2; wc3 = wn3;
        }
        float nz[2];
#pragma unroll
        for (int pf = 0; pf < 2; ++pf)
            nz[pf] = noise[(size_t)2 * BS * 4096 + b * 4096 + (wpx * 2 + pf) * 16 + (lane & 15)];
#pragma unroll
        for (int cf = 0; cf < 4; ++cf) {
            const int coB = (wco * 4 + cf) * 16 + (lane >> 4) * 4;
            float rs[4], bw[4], bb[4], sn[4];
#pragma unroll
            for (int r = 0; r < 4; ++r) {
                rs[r] = g_rstd_all[((size_t)2 * BS + b) * CCH + coB + r];
                bw[r] = Bw[2 * CCH + coB + r];
                bb[r] = Bb[2 * CCH + coB + r];
                sn[r] = style3_s[coB + r];
            }
#pragma unroll
            for (int pf = 0; pf < 2; ++pf) {
                int px = (wpx * 2 + pf) * 16 + (lane & 15);
                short4v o;
#pragma unroll
                for (int r = 0; r < 4; ++r)
                    o[r] = f2b(leaky(acc[pf][cf][r] * rs[r] + nz[pf] * bw[r] + bb[r]) * sn[r]);
                *reinterpret_cast<short4v*>(&g_bufA[((size_t)b * NS + px) * CCH + coB]) = o;
            }
        }
    }
}

// ---------------- MFMA modulated conv (NHWC bf16), layers 3..8 ----------------
template<int LW, int UPM, int TLW>
__global__ __launch_bounds__(256) void conv_mfma_kernel(
    int srcSel, int layer, int layerNext,
    const float* __restrict__ noise,
    const float* __restrict__ Bw, const float* __restrict__ Bb)
{
    constexpr int W = 1 << LW;
    constexpr int TW = 1 << TLW;
    constexpr int TH = 64 >> TLW;
    constexpr int SW = TW + 2;
    constexpr int ROWS = TH + 2;
    constexpr int NS = W * W;
    constexpr int WIN = W / 2;
    constexpr int TILES_X = W / TW;

    const short* xin = srcSel ? g_bufB : g_bufA;
    short* xout = srcSel ? g_bufA : g_bufB;

    const int b = blockIdx.y;
    const int tx = blockIdx.x & (TILES_X - 1);
    const int ty = blockIdx.x >> (LW - TLW);
    const int rowBase = ty * TH;
    const int colBase = tx * TW;
    const int tid = threadIdx.x;
    const int lane = tid & 63;
    const int wave = tid >> 6;
    const int wpx = wave & 1;
    const int wco = wave >> 1;

    __shared__ short xs[ROWS * SW * CCH];
    __shared__ float style_s[CCH];

    if (tid < CCH)
        style_s[tid] = layerNext ? g_style_all[((size_t)layerNext * BS + b) * CCH + tid] : 1.f;

    {
        const short* src = xin + (size_t)b * NS * CCH;
        const short* srcH = xin + (size_t)b * WIN * WIN * CCH;
        constexpr int UN = ROWS * SW * 16;
        for (int u = tid; u < UN; u += 256) {
            int ck = u & 15;
            int rem = u >> 4;
            int col = rem % SW;
            int rr = rem / SW;
            int gy = rowBase + rr - 1, gx = colBase + col - 1;
            short8 v = {0, 0, 0, 0, 0, 0, 0, 0};
            if (gy >= 0 && gy < W && gx >= 0 && gx < W) {
                if (UPM == 0) {
                    v = *reinterpret_cast<const short8*>(&src[((size_t)gy * W + gx) * CCH + ck * 8]);
                } else {
                    int y0, y1, x0, x1; float wy0, wy1, wx0, wx1;
                    uptaps(gy, WIN, y0, y1, wy0, wy1);
                    uptaps(gx, WIN, x0, x1, wx0, wx1);
                    short8 a00 = *reinterpret_cast<const short8*>(&srcH[((size_t)y0 * WIN + x0) * CCH + ck * 8]);
                    short8 a01 = *reinterpret_cast<const short8*>(&srcH[((size_t)y0 * WIN + x1) * CCH + ck * 8]);
                    short8 a10 = *reinterpret_cast<const short8*>(&srcH[((size_t)y1 * WIN + x0) * CCH + ck * 8]);
                    short8 a11 = *reinterpret_cast<const short8*>(&srcH[((size_t)y1 * WIN + x1) * CCH + ck * 8]);
                    float w00 = wy0 * wx0, w01 = wy0 * wx1, w10 = wy1 * wx0, w11 = wy1 * wx1;
#pragma unroll
                    for (int j = 0; j < 8; ++j)
                        v[j] = f2b(w00 * b2f(a00[j]) + w01 * b2f(a01[j])
                                 + w10 * b2f(a10[j]) + w11 * b2f(a11[j]));
                }
            }
            *reinterpret_cast<short8*>(&xs[(((rr * SW + col) * CCH) + ck * 8) ^ swz(col)]) = v;
        }
    }
    __syncthreads();

    int rL[2], cL[2];
#pragma unroll
    for (int pf = 0; pf < 2; ++pf) {
        int pl = (wpx * 2 + pf) * 16 + (lane & 15);
        cL[pf] = pl & (TW - 1);
        rL[pf] = pl >> TLW;
    }
    const int grpoff = (lane >> 4) * 8;

    f32x4 acc[2][4] = {};
    const short* wl = g_wpack + ((size_t)layer * 9 * 4 * 8 * 64
                                 + (size_t)(wco * 4) * 64 + lane) * 8;

    short8 wc0 = *reinterpret_cast<const short8*>(wl);
    short8 wc1 = *reinterpret_cast<const short8*>(wl + 512);
    short8 wc2 = *reinterpret_cast<const short8*>(wl + 1024);
    short8 wc3 = *reinterpret_cast<const short8*>(wl + 1536);
#pragma unroll
    for (int k = 0; k < 36; ++k) {
        short8 wn0 = wc0, wn1 = wc1, wn2 = wc2, wn3 = wc3;
        if (k + 1 < 36) {
            const short* wk = wl + (size_t)(k + 1) * 4096;
            wn0 = *reinterpret_cast<const short8*>(wk);
            wn1 = *reinterpret_cast<const short8*>(wk + 512);
            wn2 = *reinterpret_cast<const short8*>(wk + 1024);
            wn3 = *reinterpret_cast<const short8*>(wk + 1536);
        }
        const int tap = k >> 2, ch = k & 3;
        const int ky = tap / 3, kx = tap - ky * 3;
#pragma unroll
        for (int pf = 0; pf < 2; ++pf) {
            int col = cL[pf] + kx;
            int idx = (((rL[pf] + ky) * SW + col) * CCH + (ch << 5) + grpoff) ^ swz(col);
            short8 xf = *reinterpret_cast<const short8*>(&xs[idx]);
            acc[pf][0] = __builtin_amdgcn_mfma_f32_16x16x32_bf16(wc0, xf, acc[pf][0], 0, 0, 0);
            acc[pf][1] = __builtin_amdgcn_mfma_f32_16x16x32_bf16(wc1, xf, acc[pf][1], 0, 0, 0);
            acc[pf][2] = __builtin_amdgcn_mfma_f32_16x16x32_bf16(wc2, xf, acc[pf][2], 0, 0, 0);
            acc[pf][3] = __builtin_amdgcn_mfma_f32_16x16x32_bf16(wc3, xf, acc[pf][3], 0, 0, 0);
        }
        wc0 = wn0; wc1 = wn1; wc2 = wn2; wc3 = wn3;
    }

    float nz[2];
    int pxg[2];
#pragma unroll
    for (int pf = 0; pf < 2; ++pf) {
        int pl = (wpx * 2 + pf) * 16 + (lane & 15);
        int x = pl & (TW - 1), y = pl >> TLW;
        pxg[pf] = (rowBase + y) * W + colBase + x;
        nz[pf] = noise[b * 4096 + pxg[pf]];
    }
#pragma unroll
    for (int cf = 0; cf < 4; ++cf) {
        const int coB = (wco * 4 + cf) * 16 + (lane >> 4) * 4;
        float rs[4], bw[4], bb[4], sn[4];
#pragma unroll
        for (int r = 0; r < 4; ++r) {
            rs[r] = g_rstd_all[((size_t)layer * BS + b) * CCH + coB + r];
            bw[r] = Bw[coB + r];
            bb[r] = Bb[coB + r];
            sn[r] = style_s[coB + r];
        }
#pragma unroll
        for (int pf = 0; pf < 2; ++pf) {
            short4v o;
#pragma unroll
            for (int r = 0; r < 4; ++r) {
                float v = leaky(acc[pf][cf][r] * rs[r] + nz[pf] * bw[r] + bb[r]) * sn[r];
                o[r] = f2b(v);
            }
            *reinterpret_cast<short4v*>(&xout[((size_t)b * NS + pxg[pf]) * CCH + coB]) = o;
        }
    }
}

// ---------------- MFMA toRGB (W=64; 32x2 tiles; 3 real rows in 16-row M; waves split K) ----------------
__global__ __launch_bounds__(256) void rgb_mfma_kernel(
    int srcSel, const float* __restrict__ rgbb, float* __restrict__ out)
{
    constexpr int W = 64, TW = 32, TH = 2, SW = 34, ROWS = 4, NS = 4096;
    const short* xin = srcSel ? g_bufB : g_bufA;

    const int b = blockIdx.y;
    const int tx = blockIdx.x & 1;
    const int ty = blockIdx.x >> 1;
    const int rowBase = ty * TH;
    const int colBase = tx * TW;
    const int tid = threadIdx.x;
    const int lane = tid & 63;
    const int wave = tid >> 6;     // K-chunk

    __shared__ short xs[ROWS * SW * CCH];

    {
        const short* src = xin + (size_t)b * NS * CCH;
        constexpr int UN = ROWS * SW * 16;
        for (int u = tid; u < UN; u += 256) {
            int ck = u & 15;
            int rem = u >> 4;
            int col = rem % SW;
            int rr = rem / SW;
            int gy = rowBase + rr - 1, gx = colBase + col - 1;
            short8 v = {0, 0, 0, 0, 0, 0, 0, 0};
            if (gy >= 0 && gy < W && gx >= 0 && gx < W)
                v = *reinterpret_cast<const short8*>(&src[((size_t)gy * W + gx) * CCH + ck * 8]);
            *reinterpret_cast<short8*>(&xs[(((rr * SW + col) * CCH) + ck * 8) ^ swz(col)]) = v;
        }
    }
    __syncthreads();

    const int grpoff = (lane >> 4) * 8;
    const int cl = lane & 15;
    f32x4 acc[4] = {};
#pragma unroll
    for (int tap = 0; tap < 9; ++tap) {
        const int ky = tap / 3, kx = tap - ky * 3;
        short8 wf = *reinterpret_cast<const short8*>(
            &g_rgbpack[((size_t)(tap * 4 + wave) * 64 + lane) * 8]);
#pragma unroll
        for (int pf = 0; pf < 4; ++pf) {
            int pl = pf * 16 + cl;
            int x = pl & (TW - 1), y = pl >> 5;
            int col = x + kx;
            int idx = (((y + ky) * SW + col) * CCH + (wave << 5) + grpoff) ^ swz(col);
            short8 xf = *reinterpret_cast<const short8*>(&xs[idx]);
            acc[pf] = __builtin_amdgcn_mfma_f32_16x16x32_bf16(wf, xf, acc[pf], 0, 0, 0);
        }
    }
    __syncthreads();
    float* red = reinterpret_cast<float*>(xs);
    if (wave > 0) {
#pragma unroll
        for (int pf = 0; pf < 4; ++pf)
#pragma unroll
            for (int r = 0; r < 4; ++r)
                red[(((wave - 1) * 4 + pf) * 64 + lane) * 4 + r] = acc[pf][r];
    }
    __syncthreads();
    if (wave == 0 && (lane >> 4) == 0) {
#pragma unroll
        for (int pf = 0; pf < 4; ++pf) {
            int pl = pf * 16 + cl;
            int x = pl & (TW - 1), y = pl >> 5;
            int px = (rowBase + y) * W + colBase + x;
#pragma unroll
            for (int r = 0; r < 3; ++r) {
                float s = acc[pf][r];
#pragma unroll
                for (int wv = 0; wv < 3; ++wv)
                    s += red[((wv * 4 + pf) * 64 + lane) * 4 + r];
                out[(size_t)(b * 3 + r) * NS + px] = s + rgbb[r];
            }
        }
    }
}

// ---------------- launch ----------------
extern "C" void kernel_launch(void* const* d_in, const int* in_sizes, int n_in,
                              void* d_out, int out_size, void* d_ws, size_t ws_size,
                              hipStream_t stream)
{
    const float* latent = (const float*)d_in[0];
    const float* noise  = (const float*)d_in[1];
    const float* map_w  = (const float*)d_in[2];
    const float* map_b  = (const float*)d_in[3];
    const float* A_w    = (const float*)d_in[4];
    const float* A_b    = (const float*)d_in[5];
    const float* B_w    = (const float*)d_in[6];
    const float* B_b    = (const float*)d_in[7];
    const float* conv_w = (const float*)d_in[8];
    const float* rgb_w  = (const float*)d_in[9];
    const float* rgb_b  = (const float*)d_in[10];
    float* out = (float*)d_out;
    (void)d_ws; (void)ws_size;

    // map layer 0 (pixelnorm+FC0, writes g_w[1]) + all weight prep, one dispatch
    prep_map0_kernel<<<NMAPB + NPREPB, 256, 0, stream>>>(latent, map_w, map_b, conv_w, rgb_w);

    // mapping layers 1..7: 256 blocks each; i odd writes g_w[0] -> final w in g_w[0]
    int wsel = 1;
    for (int i = 1; i < LMAP; ++i) {
        map_fc_kernel<<<dim3(32, BS), 256, 0, stream>>>(
            wsel, map_w + (size_t)i * D * D, map_b + i * D);
        wsel ^= 1;
    }

    style_rstd_kernel<<<dim3(8, BS), 256, 0, stream>>>(A_w, A_b);

    // layers 1+2 fused (8x8) -> g_bufA
    conv8_pair_kernel<<<BS, 256, 0, stream>>>(noise, B_w, B_b);

    int cur = 0;   // data in g_bufA
    int Hc = 8;
    for (int i = 3; i < NLAYERS; ++i) {
        if (i & 1) Hc *= 2;
        int ns = Hc * Hc;
        int lnext = (i < 8) ? (i + 1) : 0;
        dim3 grid(ns / 64, BS);
        const float* nz = noise + (size_t)i * BS * 4096;
        switch (i) {
            case 3: conv_mfma_kernel<4, 1, 4><<<grid, 256, 0, stream>>>(cur, i, lnext, nz, B_w + i * CCH, B_b + i * CCH); break;
            case 4: conv_mfma_kernel<4, 0, 4><<<grid, 256, 0, stream>>>(cur, i, lnext, nz, B_w + i * CCH, B_b + i * CCH); break;
            case 5: conv_mfma_kernel<5, 1, 5><<<grid, 256, 0, stream>>>(cur, i, lnext, nz, B_w + i * CCH, B_b + i * CCH); break;
            case 6: conv_mfma_kernel<5, 0, 5><<<grid, 256, 0, stream>>>(cur, i, lnext, nz, B_w + i * CCH, B_b + i * CCH); break;
            case 7: conv_mfma_kernel<6, 1, 5><<<grid, 256, 0, stream>>>(cur, i, lnext, nz, B_w + i * CCH, B_b + i * CCH); break;
            case 8: conv_mfma_kernel<6, 0, 5><<<grid, 256, 0, stream>>>(cur, i, lnext, nz, B_w + i * CCH, B_b + i * CCH); break;
        }
        cur ^= 1;
    }

    rgb_mfma_kernel<<<dim3(64, BS), 256, 0, stream>>>(cur, rgb_b, out);
}

// Round 17
// 190.035 us; speedup vs baseline: 1.2679x; 1.0254x over previous
//
#include <hip/hip_runtime.h>
#include <hip/hip_bf16.h>

#define BS 8
#define D 512
#define CCH 128
#define LMAP 8
#define NLAYERS 9

typedef short short8 __attribute__((ext_vector_type(8)));
typedef short short4v __attribute__((ext_vector_type(4)));
typedef float f32x4 __attribute__((ext_vector_type(4)));

// ---- module-global scratch ----
__device__ short g_bufA[(size_t)BS * 4096 * CCH];   // bf16 NHWC [b][px][ci]
__device__ short g_bufB[(size_t)BS * 4096 * CCH];
__device__ float g_w[2][BS * D];
__device__ float g_style_all[NLAYERS * BS * CCH];
__device__ float g_rstd_all[NLAYERS * BS * CCH];
__device__ float g_s2[(size_t)NLAYERS * CCH * CCH];              // S2[l][co][ci] = sum_tap w^2
__device__ short g_wpack[(size_t)NLAYERS * 9 * 4 * 8 * 64 * 8];  // packed bf16 W-frags
__device__ short g_rgbpack[9 * 4 * 64 * 8];

__device__ __forceinline__ float leaky(float v) { return v >= 0.f ? v : 0.2f * v; }
__device__ __forceinline__ short f2b(float f) {
    __hip_bfloat16 h = __float2bfloat16(f);
    return *reinterpret_cast<short*>(&h);
}
__device__ __forceinline__ float b2f(short s) {
    return __uint_as_float(((unsigned int)(unsigned short)s) << 16);
}
__device__ __forceinline__ int swz(int col) { return ((col ^ (col >> 3)) & 7) << 3; }

__device__ __forceinline__ void uptaps(int o, int Win, int& i0, int& i1, float& w0, float& w1)
{
    int m = o >> 1;
    if ((o & 1) == 0) { i0 = m - 1; i1 = m; w0 = 0.25f; w1 = 0.75f; if (i0 < 0) { i0 = 0; w0 = 0.f; w1 = 1.f; } }
    else              { i0 = m; i1 = m + 1; w0 = 0.75f; w1 = 0.25f; if (i1 >= Win) { i1 = Win - 1; w0 = 1.f; w1 = 0.f; } }
}

#define WPN (NLAYERS * 9 * 4 * 8 * 64)
#define RGBN (9 * 4 * 64)
#define S2N (NLAYERS * CCH * CCH)
#define NPREPB ((WPN + RGBN + S2N + 255) / 256)
#define NMAPB (32 * BS)

// ---------------- fused: map layer 0 (pixelnorm + FC0) + prep ----------------
__global__ __launch_bounds__(256) void prep_map0_kernel(
    const float* __restrict__ z, const float* __restrict__ W0, const float* __restrict__ b0,
    const float* __restrict__ convw, const float* __restrict__ rgbw)
{
    const int bid = blockIdx.x;
    const int tid = threadIdx.x;
    if (bid < NMAPB) {
        const int jt = bid & 31, b = bid >> 5;
        const int jb = jt * 16;
        const int jl = tid & 15, kp = tid >> 4;
        __shared__ float xin[D];
        __shared__ float part[16][16];
        __shared__ float wred[4];
        xin[tid] = z[b * D + tid];
        xin[tid + 256] = z[b * D + tid + 256];
        __syncthreads();
        {
            float p = xin[tid] * xin[tid] + xin[tid + 256] * xin[tid + 256];
#pragma unroll
            for (int off = 32; off > 0; off >>= 1) p += __shfl_down(p, off, 64);
            if ((tid & 63) == 0) wred[tid >> 6] = p;
            __syncthreads();
            float ss = wred[0] + wred[1] + wred[2] + wred[3];
            float r = rsqrtf(ss * (1.f / 512.f) + 1e-8f);
            xin[tid] *= r; xin[tid + 256] *= r;
            __syncthreads();
        }
        const float* Wp = W0 + jb + jl;
        const int k0 = kp * 32;
        float a[16];
#pragma unroll
        for (int j = 0; j < 16; ++j) a[j] = 0.f;
#pragma unroll
        for (int k = k0; k < k0 + 32; k += 16) {
#pragma unroll
            for (int j = 0; j < 16; ++j)
                a[j] += xin[k + j] * Wp[(size_t)(k + j) * D];
        }
        float s16 = 0.f;
#pragma unroll
        for (int j = 0; j < 16; ++j) s16 += a[j];
        part[kp][jl] = s16;
        __syncthreads();
        if (tid < 16) {
            float s = b0[jb + tid];
#pragma unroll
            for (int p = 0; p < 16; ++p) s += part[p][tid];
            g_w[1][b * D + jb + tid] = leaky(s);
        }
        return;
    }
    int idx = (bid - NMAPB) * 256 + tid;
    if (idx < WPN) {
        int lane = idx & 63;
        int cogrp = (idx >> 6) & 7;
        int chunk = (idx >> 9) & 3;
        int t = idx >> 11;
        int layer = t / 9, tap = t - layer * 9;
        int co = cogrp * 16 + (lane & 15);
        int ci0 = chunk * 32 + (lane >> 4) * 8;
        short8 v;
#pragma unroll
        for (int j = 0; j < 8; ++j)
            v[j] = f2b(convw[(((size_t)layer * CCH + co) * CCH + ci0 + j) * 9 + tap]);
        *reinterpret_cast<short8*>(&g_wpack[(size_t)idx * 8]) = v;
    } else if (idx < WPN + RGBN) {
        int u = idx - WPN;
        int lane = u & 63;
        int chunk = (u >> 6) & 3;
        int tap = u >> 8;
        int co = lane & 15;
        int ci0 = chunk * 32 + (lane >> 4) * 8;
        short8 v;
#pragma unroll
        for (int j = 0; j < 8; ++j)
            v[j] = (co < 3) ? f2b(rgbw[((size_t)(co * CCH) + ci0 + j) * 9 + tap]) : (short)0;
        *reinterpret_cast<short8*>(&g_rgbpack[(size_t)u * 8]) = v;
    } else if (idx < WPN + RGBN + S2N) {
        int u = idx - WPN - RGBN;         // [l][co][ci]
        const float* wp = convw + (size_t)u * 9;
        float s = 0.f;
#pragma unroll
        for (int t = 0; t < 9; ++t) { float m = wp[t]; s += m * m; }
        g_s2[u] = s;
    }
}

// ---------------- Mapping FC layers 1..7: 256 blocks/layer, 16 j x 16 k-parts, ILP-16 ----------------
__global__ __launch_bounds__(256) void map_fc_kernel(
    int srcSel, const float* __restrict__ W, const float* __restrict__ bias)
{
    float* wout = g_w[srcSel ^ 1];
    int b = blockIdx.y;
    int jb = blockIdx.x * 16;
    int tid = threadIdx.x;
    int jl = tid & 15, kp = tid >> 4;
    __shared__ float xin[D];
    __shared__ float part[16][16];
    const float* win = g_w[srcSel];
    xin[tid] = win[b * D + tid];
    xin[tid + 256] = win[b * D + tid + 256];
    __syncthreads();
    const float* Wp = W + jb + jl;
    const int k0 = kp * 32;
    float a[16];
#pragma unroll
    for (int j = 0; j < 16; ++j) a[j] = 0.f;
#pragma unroll
    for (int k = k0; k < k0 + 32; k += 16) {
#pragma unroll
        for (int j = 0; j < 16; ++j)
            a[j] += xin[k + j] * Wp[(size_t)(k + j) * D];
    }
    float s16 = 0.f;
#pragma unroll
    for (int j = 0; j < 16; ++j) s16 += a[j];
    part[kp][jl] = s16;
    __syncthreads();
    if (tid < 16) {
        float s = bias[jb + tid];
#pragma unroll
        for (int p = 0; p < 16; ++p) s += part[p][tid];
        wout[b * D + jb + tid] = leaky(s);
    }
}

// ---------------- style + rstd for ALL layers (rstd via S2), one dispatch ----------------
__global__ __launch_bounds__(256) void style_rstd_kernel(
    const float* __restrict__ Aw, const float* __restrict__ Ab)
{
    int l = blockIdx.x + 1;        // layers 1..8
    int b = blockIdx.y;
    int tid = threadIdx.x;
    __shared__ float ws_[D];
    __shared__ float part[2][CCH];
    __shared__ float st[CCH];
    ws_[tid] = g_w[0][b * D + tid];
    ws_[tid + 256] = g_w[0][b * D + tid + 256];
    __syncthreads();
    {
        int c = tid & 127, kh = tid >> 7;
        const float* Ap = Aw + (size_t)l * D * CCH + c;
        const int k0 = kh * 256;
        float a0 = 0.f, a1 = 0.f, a2 = 0.f, a3 = 0.f, a4 = 0.f, a5 = 0.f, a6 = 0.f, a7 = 0.f;
        for (int k = k0; k < k0 + 256; k += 8) {
            a0 += ws_[k + 0] * Ap[(size_t)(k + 0) * CCH];
            a1 += ws_[k + 1] * Ap[(size_t)(k + 1) * CCH];
            a2 += ws_[k + 2] * Ap[(size_t)(k + 2) * CCH];
            a3 += ws_[k + 3] * Ap[(size_t)(k + 3) * CCH];
            a4 += ws_[k + 4] * Ap[(size_t)(k + 4) * CCH];
            a5 += ws_[k + 5] * Ap[(size_t)(k + 5) * CCH];
            a6 += ws_[k + 6] * Ap[(size_t)(k + 6) * CCH];
            a7 += ws_[k + 7] * Ap[(size_t)(k + 7) * CCH];
        }
        part[kh][c] = ((a0 + a1) + (a2 + a3)) + ((a4 + a5) + (a6 + a7));
    }
    __syncthreads();
    if (tid < CCH) {
        float s = part[0][tid] + part[1][tid] + Ab[l * CCH + tid];
        st[tid] = s;
        g_style_all[((size_t)l * BS + b) * CCH + tid] = s;
    }
    __syncthreads();
    int colid = tid >> 4, kpart = tid & 15;
#pragma unroll
    for (int co8 = 0; co8 < 8; ++co8) {
        int cout = co8 * 16 + colid;
        const float* sp = g_s2 + ((size_t)l * CCH + cout) * CCH + kpart * 8;
        float s = 0.f;
#pragma unroll
        for (int j = 0; j < 8; ++j) { float sv = st[kpart * 8 + j]; s += sv * sv * sp[j]; }
#pragma unroll
        for (int off = 8; off > 0; off >>= 1) s += __shfl_down(s, off, 16);
        if (kpart == 0) g_rstd_all[((size_t)l * BS + b) * CCH + cout] = rsqrtf(s + 1e-8f);
    }
}

// ---------------- fused conv layers 1+2 (both 8x8), one block per batch ----------------
__global__ __launch_bounds__(256) void conv8_pair_kernel(
    const float* __restrict__ noise,
    const float* __restrict__ Bw, const float* __restrict__ Bb)
{
    constexpr int W = 8, SW = 10, ROWS = 10, NS = 64, WIN = 4;
    const int b = blockIdx.x;
    const int tid = threadIdx.x;
    const int lane = tid & 63;
    const int wave = tid >> 6;
    const int wpx = wave & 1;
    const int wco = wave >> 1;

    __shared__ short xs1[ROWS * SW * CCH];
    __shared__ short xs2[ROWS * SW * CCH];
    __shared__ short sm[16 * CCH];
    __shared__ float style2_s[CCH], style3_s[CCH];

    if (tid < CCH) {
        style2_s[tid] = g_style_all[((size_t)2 * BS + b) * CCH + tid];
        style3_s[tid] = g_style_all[((size_t)3 * BS + b) * CCH + tid];
    }
    for (int u = tid; u < 16 * CCH; u += 256) {
        int c = u & 127;
        int pp = u >> 7;
        float v = leaky(noise[b * 4096 + pp] * Bw[c] + Bb[c])
                  * g_style_all[((size_t)1 * BS + b) * CCH + c];
        sm[u] = f2b(v);
    }
    for (int u = tid; u < ROWS * SW * 16; u += 256) {
        int ck = u & 15;
        int cell = u >> 4;
        int col = cell % SW;
        int rr = cell / SW;
        if (rr >= 1 && rr <= 8 && col >= 1 && col <= 8) continue;
        short8 zz = {0, 0, 0, 0, 0, 0, 0, 0};
        *reinterpret_cast<short8*>(&xs2[(((rr * SW + col) * CCH) + ck * 8) ^ swz(col)]) = zz;
    }
    __syncthreads();

    for (int u = tid; u < ROWS * SW * 16; u += 256) {
        int ck = u & 15;
        int rem = u >> 4;
        int col = rem % SW;
        int rr = rem / SW;
        int gy = rr - 1, gx = col - 1;
        short8 v = {0, 0, 0, 0, 0, 0, 0, 0};
        if (gy >= 0 && gy < W && gx >= 0 && gx < W) {
            int y0, y1, x0, x1; float wy0, wy1, wx0, wx1;
            uptaps(gy, WIN, y0, y1, wy0, wy1);
            uptaps(gx, WIN, x0, x1, wx0, wx1);
            short8 a00 = *reinterpret_cast<const short8*>(&sm[((size_t)y0 * WIN + x0) * CCH + ck * 8]);
            short8 a01 = *reinterpret_cast<const short8*>(&sm[((size_t)y0 * WIN + x1) * CCH + ck * 8]);
            short8 a10 = *reinterpret_cast<const short8*>(&sm[((size_t)y1 * WIN + x0) * CCH + ck * 8]);
            short8 a11 = *reinterpret_cast<const short8*>(&sm[((size_t)y1 * WIN + x1) * CCH + ck * 8]);
            float w00 = wy0 * wx0, w01 = wy0 * wx1, w10 = wy1 * wx0, w11 = wy1 * wx1;
#pragma unroll
            for (int j = 0; j < 8; ++j)
                v[j] = f2b(w00 * b2f(a00[j]) + w01 * b2f(a01[j])
                         + w10 * b2f(a10[j]) + w11 * b2f(a11[j]));
        }
        *reinterpret_cast<short8*>(&xs1[(((rr * SW + col) * CCH) + ck * 8) ^ swz(col)]) = v;
    }
    __syncthreads();

    int rL[2], cL[2];
#pragma unroll
    for (int pf = 0; pf < 2; ++pf) {
        int pl = (wpx * 2 + pf) * 16 + (lane & 15);
        cL[pf] = pl & (W - 1);
        rL[pf] = pl >> 3;
    }
    const int grpoff = (lane >> 4) * 8;

    // phase A: conv layer 1 -> xs2
    {
        f32x4 acc[2][4] = {};
        const short* wl = g_wpack + ((size_t)1 * 9 * 4 * 8 * 64 + (size_t)(wco * 4) * 64 + lane) * 8;
        short8 wc0 = *reinterpret_cast<const short8*>(wl);
        short8 wc1 = *reinterpret_cast<const short8*>(wl + 512);
        short8 wc2 = *reinterpret_cast<const short8*>(wl + 1024);
        short8 wc3 = *reinterpret_cast<const short8*>(wl + 1536);
#pragma unroll
        for (int k = 0; k < 36; ++k) {
            short8 wn0 = wc0, wn1 = wc1, wn2 = wc2, wn3 = wc3;
            if (k + 1 < 36) {
                const short* wk = wl + (size_t)(k + 1) * 4096;
                wn0 = *reinterpret_cast<const short8*>(wk);
                wn1 = *reinterpret_cast<const short8*>(wk + 512);
                wn2 = *reinterpret_cast<const short8*>(wk + 1024);
                wn3 = *reinterpret_cast<const short8*>(wk + 1536);
            }
            const int tap = k >> 2, ch = k & 3;
            const int ky = tap / 3, kx = tap - ky * 3;
#pragma unroll
            for (int pf = 0; pf < 2; ++pf) {
                int col = cL[pf] + kx;
                int idx = (((rL[pf] + ky) * SW + col) * CCH + (ch << 5) + grpoff) ^ swz(col);
                short8 xf = *reinterpret_cast<const short8*>(&xs1[idx]);
                acc[pf][0] = __builtin_amdgcn_mfma_f32_16x16x32_bf16(wc0, xf, acc[pf][0], 0, 0, 0);
                acc[pf][1] = __builtin_amdgcn_mfma_f32_16x16x32_bf16(wc1, xf, acc[pf][1], 0, 0, 0);
                acc[pf][2] = __builtin_amdgcn_mfma_f32_16x16x32_bf16(wc2, xf, acc[pf][2], 0, 0, 0);
                acc[pf][3] = __builtin_amdgcn_mfma_f32_16x16x32_bf16(wc3, xf, acc[pf][3], 0, 0, 0);
            }
            wc0 = wn0; wc1 = wn1; wc2 = wn2; wc3 = wn3;
        }
        float nz[2];
#pragma unroll
        for (int pf = 0; pf < 2; ++pf)
            nz[pf] = noise[(size_t)BS * 4096 + b * 4096 + (wpx * 2 + pf) * 16 + (lane & 15)];
#pragma unroll
        for (int cf = 0; cf < 4; ++cf) {
            const int coB = (wco * 4 + cf) * 16 + (lane >> 4) * 4;
            float rs[4], bw[4], bb[4], sn[4];
#pragma unroll
            for (int r = 0; r < 4; ++r) {
                rs[r] = g_rstd_all[((size_t)1 * BS + b) * CCH + coB + r];
                bw[r] = Bw[1 * CCH + coB + r];
                bb[r] = Bb[1 * CCH + coB + r];
                sn[r] = style2_s[coB + r];
            }
#pragma unroll
            for (int pf = 0; pf < 2; ++pf) {
                int px = (wpx * 2 + pf) * 16 + (lane & 15);
                int y = px >> 3, x = px & 7;
                short4v o;
#pragma unroll
                for (int r = 0; r < 4; ++r)
                    o[r] = f2b(leaky(acc[pf][cf][r] * rs[r] + nz[pf] * bw[r] + bb[r]) * sn[r]);
                int col = x + 1;
                *reinterpret_cast<short4v*>(&xs2[((((y + 1) * SW + col) * CCH) + coB) ^ swz(col)]) = o;
            }
        }
    }
    __syncthreads();

    // phase B: conv layer 2 -> global
    {
        f32x4 acc[2][4] = {};
        const short* wl = g_wpack + ((size_t)2 * 9 * 4 * 8 * 64 + (size_t)(wco * 4) * 64 + lane) * 8;
        short8 wc0 = *reinterpret_cast<const short8*>(wl);
        short8 wc1 = *reinterpret_cast<const short8*>(wl + 512);
        short8 wc2 = *reinterpret_cast<const short8*>(wl + 1024);
        short8 wc3 = *reinterpret_cast<const short8*>(wl + 1536);
#pragma unroll
        for (int k = 0; k < 36; ++k) {
            short8 wn0 = wc0, wn1 = wc1, wn2 = wc2, wn3 = wc3;
            if (k + 1 < 36) {
                const short* wk = wl + (size_t)(k + 1) * 4096;
                wn0 = *reinterpret_cast<const short8*>(wk);
                wn1 = *reinterpret_cast<const short8*>(wk + 512);
                wn2 = *reinterpret_cast<const short8*>(wk + 1024);
                wn3 = *reinterpret_cast<const short8*>(wk + 1536);
            }
            const int tap = k >> 2, ch = k & 3;
            const int ky = tap / 3, kx = tap - ky * 3;
#pragma unroll
            for (int pf = 0; pf < 2; ++pf) {
                int col = cL[pf] + kx;
                int idx = (((rL[pf] + ky) * SW + col) * CCH + (ch << 5) + grpoff) ^ swz(col);
                short8 xf = *reinterpret_cast<const short8*>(&xs2[idx]);
                acc[pf][0] = __builtin_amdgcn_mfma_f32_16x16x32_bf16(wc0, xf, acc[pf][0], 0, 0, 0);
                acc[pf][1] = __builtin_amdgcn_mfma_f32_16x16x32_bf16(wc1, xf, acc[pf][1], 0, 0, 0);
                acc[pf][2] = __builtin_amdgcn_mfma_f32_16x16x32_bf16(wc2, xf, acc[pf][2], 0, 0, 0);
                acc[pf][3] = __builtin_amdgcn_mfma_f32_16x16x32_bf16(wc3, xf, acc[pf][3], 0, 0, 0);
            }
            wc0 = wn0; wc1 = wn1; wc2 = wn2; wc3 = wn3;
        }
        float nz[2];
#pragma unroll
        for (int pf = 0; pf < 2; ++pf)
            nz[pf] = noise[(size_t)2 * BS * 4096 + b * 4096 + (wpx * 2 + pf) * 16 + (lane & 15)];
#pragma unroll
        for (int cf = 0; cf < 4; ++cf) {
            const int coB = (wco * 4 + cf) * 16 + (lane >> 4) * 4;
            float rs[4], bw[4], bb[4], sn[4];
#pragma unroll
            for (int r = 0; r < 4; ++r) {
                rs[r] = g_rstd_all[((size_t)2 * BS + b) * CCH + coB + r];
                bw[r] = Bw[2 * CCH + coB + r];
                bb[r] = Bb[2 * CCH + coB + r];
                sn[r] = style3_s[coB + r];
            }
#pragma unroll
            for (int pf = 0; pf < 2; ++pf) {
                int px = (wpx * 2 + pf) * 16 + (lane & 15);
                short4v o;
#pragma unroll
                for (int r = 0; r < 4; ++r)
                    o[r] = f2b(leaky(acc[pf][cf][r] * rs[r] + nz[pf] * bw[r] + bb[r]) * sn[r]);
                *reinterpret_cast<short4v*>(&g_bufA[((size_t)b * NS + px) * CCH + coB]) = o;
            }
        }
    }
}

// ---------------- MFMA modulated conv (NHWC bf16), layers 3..8 ----------------
// 1D grid, XCD-batch affinity: b = blockIdx.x & 7 (pins batch to XCD), tile = blockIdx.x >> 3.
template<int LW, int UPM, int TLW>
__global__ __launch_bounds__(256) void conv_mfma_kernel(
    int srcSel, int layer, int layerNext,
    const float* __restrict__ noise,
    const float* __restrict__ Bw, const float* __restrict__ Bb)
{
    constexpr int W = 1 << LW;
    constexpr int TW = 1 << TLW;
    constexpr int TH = 64 >> TLW;
    constexpr int SW = TW + 2;
    constexpr int ROWS = TH + 2;
    constexpr int NS = W * W;
    constexpr int WIN = W / 2;
    constexpr int TILES_X = W / TW;

    const short* xin = srcSel ? g_bufB : g_bufA;
    short* xout = srcSel ? g_bufA : g_bufB;

    const int b = blockIdx.x & 7;            // XCD-batch affinity
    const int tileid = blockIdx.x >> 3;
    const int tx = tileid & (TILES_X - 1);
    const int ty = tileid >> (LW - TLW);
    const int rowBase = ty * TH;
    const int colBase = tx * TW;
    const int tid = threadIdx.x;
    const int lane = tid & 63;
    const int wave = tid >> 6;
    const int wpx = wave & 1;
    const int wco = wave >> 1;

    __shared__ short xs[ROWS * SW * CCH];
    __shared__ float style_s[CCH];

    if (tid < CCH)
        style_s[tid] = layerNext ? g_style_all[((size_t)layerNext * BS + b) * CCH + tid] : 1.f;

    {
        const short* src = xin + (size_t)b * NS * CCH;
        const short* srcH = xin + (size_t)b * WIN * WIN * CCH;
        constexpr int UN = ROWS * SW * 16;
        for (int u = tid; u < UN; u += 256) {
            int ck = u & 15;
            int rem = u >> 4;
            int col = rem % SW;
            int rr = rem / SW;
            int gy = rowBase + rr - 1, gx = colBase + col - 1;
            short8 v = {0, 0, 0, 0, 0, 0, 0, 0};
            if (gy >= 0 && gy < W && gx >= 0 && gx < W) {
                if (UPM == 0) {
                    v = *reinterpret_cast<const short8*>(&src[((size_t)gy * W + gx) * CCH + ck * 8]);
                } else {
                    int y0, y1, x0, x1; float wy0, wy1, wx0, wx1;
                    uptaps(gy, WIN, y0, y1, wy0, wy1);
                    uptaps(gx, WIN, x0, x1, wx0, wx1);
                    short8 a00 = *reinterpret_cast<const short8*>(&srcH[((size_t)y0 * WIN + x0) * CCH + ck * 8]);
                    short8 a01 = *reinterpret_cast<const short8*>(&srcH[((size_t)y0 * WIN + x1) * CCH + ck * 8]);
                    short8 a10 = *reinterpret_cast<const short8*>(&srcH[((size_t)y1 * WIN + x0) * CCH + ck * 8]);
                    short8 a11 = *reinterpret_cast<const short8*>(&srcH[((size_t)y1 * WIN + x1) * CCH + ck * 8]);
                    float w00 = wy0 * wx0, w01 = wy0 * wx1, w10 = wy1 * wx0, w11 = wy1 * wx1;
#pragma unroll
                    for (int j = 0; j < 8; ++j)
                        v[j] = f2b(w00 * b2f(a00[j]) + w01 * b2f(a01[j])
                                 + w10 * b2f(a10[j]) + w11 * b2f(a11[j]));
                }
            }
            *reinterpret_cast<short8*>(&xs[(((rr * SW + col) * CCH) + ck * 8) ^ swz(col)]) = v;
        }
    }
    __syncthreads();

    int rL[2], cL[2];
#pragma unroll
    for (int pf = 0; pf < 2; ++pf) {
        int pl = (wpx * 2 + pf) * 16 + (lane & 15);
        cL[pf] = pl & (TW - 1);
        rL[pf] = pl >> TLW;
    }
    const int grpoff = (lane >> 4) * 8;

    f32x4 acc[2][4] = {};
    const short* wl = g_wpack + ((size_t)layer * 9 * 4 * 8 * 64
                                 + (size_t)(wco * 4) * 64 + lane) * 8;

    short8 wc0 = *reinterpret_cast<const short8*>(wl);
    short8 wc1 = *reinterpret_cast<const short8*>(wl + 512);
    short8 wc2 = *reinterpret_cast<const short8*>(wl + 1024);
    short8 wc3 = *reinterpret_cast<const short8*>(wl + 1536);
#pragma unroll
    for (int k = 0; k < 36; ++k) {
        short8 wn0 = wc0, wn1 = wc1, wn2 = wc2, wn3 = wc3;
        if (k + 1 < 36) {
            const short* wk = wl + (size_t)(k + 1) * 4096;
            wn0 = *reinterpret_cast<const short8*>(wk);
            wn1 = *reinterpret_cast<const short8*>(wk + 512);
            wn2 = *reinterpret_cast<const short8*>(wk + 1024);
            wn3 = *reinterpret_cast<const short8*>(wk + 1536);
        }
        const int tap = k >> 2, ch = k & 3;
        const int ky = tap / 3, kx = tap - ky * 3;
#pragma unroll
        for (int pf = 0; pf < 2; ++pf) {
            int col = cL[pf] + kx;
            int idx = (((rL[pf] + ky) * SW + col) * CCH + (ch << 5) + grpoff) ^ swz(col);
            short8 xf = *reinterpret_cast<const short8*>(&xs[idx]);
            acc[pf][0] = __builtin_amdgcn_mfma_f32_16x16x32_bf16(wc0, xf, acc[pf][0], 0, 0, 0);
            acc[pf][1] = __builtin_amdgcn_mfma_f32_16x16x32_bf16(wc1, xf, acc[pf][1], 0, 0, 0);
            acc[pf][2] = __builtin_amdgcn_mfma_f32_16x16x32_bf16(wc2, xf, acc[pf][2], 0, 0, 0);
            acc[pf][3] = __builtin_amdgcn_mfma_f32_16x16x32_bf16(wc3, xf, acc[pf][3], 0, 0, 0);
        }
        wc0 = wn0; wc1 = wn1; wc2 = wn2; wc3 = wn3;
    }

    float nz[2];
    int pxg[2];
#pragma unroll
    for (int pf = 0; pf < 2; ++pf) {
        int pl = (wpx * 2 + pf) * 16 + (lane & 15);
        int x = pl & (TW - 1), y = pl >> TLW;
        pxg[pf] = (rowBase + y) * W + colBase + x;
        nz[pf] = noise[b * 4096 + pxg[pf]];
    }
#pragma unroll
    for (int cf = 0; cf < 4; ++cf) {
        const int coB = (wco * 4 + cf) * 16 + (lane >> 4) * 4;
        float rs[4], bw[4], bb[4], sn[4];
#pragma unroll
        for (int r = 0; r < 4; ++r) {
            rs[r] = g_rstd_all[((size_t)layer * BS + b) * CCH + coB + r];
            bw[r] = Bw[coB + r];
            bb[r] = Bb[coB + r];
            sn[r] = style_s[coB + r];
        }
#pragma unroll
        for (int pf = 0; pf < 2; ++pf) {
            short4v o;
#pragma unroll
            for (int r = 0; r < 4; ++r) {
                float v = leaky(acc[pf][cf][r] * rs[r] + nz[pf] * bw[r] + bb[r]) * sn[r];
                o[r] = f2b(v);
            }
            *reinterpret_cast<short4v*>(&xout[((size_t)b * NS + pxg[pf]) * CCH + coB]) = o;
        }
    }
}

// ---------------- MFMA toRGB (W=64; 32x2 tiles; XCD-batch affinity) ----------------
__global__ __launch_bounds__(256) void rgb_mfma_kernel(
    int srcSel, const float* __restrict__ rgbb, float* __restrict__ out)
{
    constexpr int W = 64, TW = 32, TH = 2, SW = 34, ROWS = 4, NS = 4096;
    const short* xin = srcSel ? g_bufB : g_bufA;

    const int b = blockIdx.x & 7;
    const int tileid = blockIdx.x >> 3;
    const int tx = tileid & 1;
    const int ty = tileid >> 1;
    const int rowBase = ty * TH;
    const int colBase = tx * TW;
    const int tid = threadIdx.x;
    const int lane = tid & 63;
    const int wave = tid >> 6;     // K-chunk

    __shared__ short xs[ROWS * SW * CCH];

    {
        const short* src = xin + (size_t)b * NS * CCH;
        constexpr int UN = ROWS * SW * 16;
        for (int u = tid; u < UN; u += 256) {
            int ck = u & 15;
            int rem = u >> 4;
            int col = rem % SW;
            int rr = rem / SW;
            int gy = rowBase + rr - 1, gx = colBase + col - 1;
            short8 v = {0, 0, 0, 0, 0, 0, 0, 0};
            if (gy >= 0 && gy < W && gx >= 0 && gx < W)
                v = *reinterpret_cast<const short8*>(&src[((size_t)gy * W + gx) * CCH + ck * 8]);
            *reinterpret_cast<short8*>(&xs[(((rr * SW + col) * CCH) + ck * 8) ^ swz(col)]) = v;
        }
    }
    __syncthreads();

    const int grpoff = (lane >> 4) * 8;
    const int cl = lane & 15;
    f32x4 acc[4] = {};
#pragma unroll
    for (int tap = 0; tap < 9; ++tap) {
        const int ky = tap / 3, kx = tap - ky * 3;
        short8 wf = *reinterpret_cast<const short8*>(
            &g_rgbpack[((size_t)(tap * 4 + wave) * 64 + lane) * 8]);
#pragma unroll
        for (int pf = 0; pf < 4; ++pf) {
            int pl = pf * 16 + cl;
            int x = pl & (TW - 1), y = pl >> 5;
            int col = x + kx;
            int idx = (((y + ky) * SW + col) * CCH + (wave << 5) + grpoff) ^ swz(col);
            short8 xf = *reinterpret_cast<const short8*>(&xs[idx]);
            acc[pf] = __builtin_amdgcn_mfma_f32_16x16x32_bf16(wf, xf, acc[pf], 0, 0, 0);
        }
    }
    __syncthreads();
    float* red = reinterpret_cast<float*>(xs);
    if (wave > 0) {
#pragma unroll
        for (int pf = 0; pf < 4; ++pf)
#pragma unroll
            for (int r = 0; r < 4; ++r)
                red[(((wave - 1) * 4 + pf) * 64 + lane) * 4 + r] = acc[pf][r];
    }
    __syncthreads();
    if (wave == 0 && (lane >> 4) == 0) {
#pragma unroll
        for (int pf = 0; pf < 4; ++pf) {
            int pl = pf * 16 + cl;
            int x = pl & (TW - 1), y = pl >> 5;
            int px = (rowBase + y) * W + colBase + x;
#pragma unroll
            for (int r = 0; r < 3; ++r) {
                float s = acc[pf][r];
#pragma unroll
                for (int wv = 0; wv < 3; ++wv)
                    s += red[((wv * 4 + pf) * 64 + lane) * 4 + r];
                out[(size_t)(b * 3 + r) * NS + px] = s + rgbb[r];
            }
        }
    }
}

// ---------------- launch ----------------
extern "C" void kernel_launch(void* const* d_in, const int* in_sizes, int n_in,
                              void* d_out, int out_size, void* d_ws, size_t ws_size,
                              hipStream_t stream)
{
    const float* latent = (const float*)d_in[0];
    const float* noise  = (const float*)d_in[1];
    const float* map_w  = (const float*)d_in[2];
    const float* map_b  = (const float*)d_in[3];
    const float* A_w    = (const float*)d_in[4];
    const float* A_b    = (const float*)d_in[5];
    const float* B_w    = (const float*)d_in[6];
    const float* B_b    = (const float*)d_in[7];
    const float* conv_w = (const float*)d_in[8];
    const float* rgb_w  = (const float*)d_in[9];
    const float* rgb_b  = (const float*)d_in[10];
    float* out = (float*)d_out;
    (void)d_ws; (void)ws_size;

    prep_map0_kernel<<<NMAPB + NPREPB, 256, 0, stream>>>(latent, map_w, map_b, conv_w, rgb_w);

    int wsel = 1;
    for (int i = 1; i < LMAP; ++i) {
        map_fc_kernel<<<dim3(32, BS), 256, 0, stream>>>(
            wsel, map_w + (size_t)i * D * D, map_b + i * D);
        wsel ^= 1;
    }

    style_rstd_kernel<<<dim3(8, BS), 256, 0, stream>>>(A_w, A_b);

    conv8_pair_kernel<<<BS, 256, 0, stream>>>(noise, B_w, B_b);

    int cur = 0;   // data in g_bufA
    int Hc = 8;
    for (int i = 3; i < NLAYERS; ++i) {
        if (i & 1) Hc *= 2;
        int ns = Hc * Hc;
        int lnext = (i < 8) ? (i + 1) : 0;
        int nblk = (ns / 64) * BS;     // 1D grid, b = bid & 7
        const float* nz = noise + (size_t)i * BS * 4096;
        switch (i) {
            case 3: conv_mfma_kernel<4, 1, 4><<<nblk, 256, 0, stream>>>(cur, i, lnext, nz, B_w + i * CCH, B_b + i * CCH); break;
            case 4: conv_mfma_kernel<4, 0, 4><<<nblk, 256, 0, stream>>>(cur, i, lnext, nz, B_w + i * CCH, B_b + i * CCH); break;
            case 5: conv_mfma_kernel<5, 1, 5><<<nblk, 256, 0, stream>>>(cur, i, lnext, nz, B_w + i * CCH, B_b + i * CCH); break;
            case 6: conv_mfma_kernel<5, 0, 5><<<nblk, 256, 0, stream>>>(cur, i, lnext, nz, B_w + i * CCH, B_b + i * CCH); break;
            case 7: conv_mfma_kernel<6, 1, 5><<<nblk, 256, 0, stream>>>(cur, i, lnext, nz, B_w + i * CCH, B_b + i * CCH); break;
            case 8: conv_mfma_kernel<6, 0, 5><<<nblk, 256, 0, stream>>>(cur, i, lnext, nz, B_w + i * CCH, B_b + i * CCH); break;
        }
        cur ^= 1;
    }

    rgb_mfma_kernel<<<64 * BS, 256, 0, stream>>>(cur, rgb_b, out);
}